// Round 5
// baseline (443.333 us; speedup 1.0000x reference)
//
#include <hip/hip_runtime.h>
#include <hip/hip_bf16.h>
#include <stdint.h>

#define T_TOK 4096
#define H_DIM 1024
#define F_DIM 2816
#define NE 8
#define NTILE_MAX 72   // >= sum_e ceil(Ne/128) worst case (64 + 7 partials)

using bf16x8 = __attribute__((ext_vector_type(8))) short;   // 8 bf16 in 4 VGPRs
using f32x4  = __attribute__((ext_vector_type(4))) float;   // MFMA accumulator

// RNE float -> bf16 bits (finite inputs only)
__device__ __forceinline__ unsigned short f2bf(float f) {
    union { float f; uint32_t u; } v; v.f = f;
    uint32_t r = v.u + 0x7FFFu + ((v.u >> 16) & 1u);
    return (unsigned short)(r >> 16);
}

// async global->LDS, 16B per lane. lds dest: wave-uniform base + lane*16.
__device__ __forceinline__ void gload_lds16(const void* gsrc, void* lds) {
    __builtin_amdgcn_global_load_lds(
        (const __attribute__((address_space(1))) uint32_t*)gsrc,
        (__attribute__((address_space(3))) uint32_t*)lds, 16, 0, 0);
}

// ---------------- router: one wave per token; also emits xbf (bf16 cast of x) ----------------
__global__ __launch_bounds__(256) void router_kernel(
    const float* __restrict__ x, const float* __restrict__ wr,
    unsigned short* __restrict__ xbf,
    int* __restrict__ top_i, float* __restrict__ top_w, int* __restrict__ counts)
{
    const int w = threadIdx.x >> 6, l = threadIdx.x & 63;
    const int tok = blockIdx.x * 4 + w;
    const float* xrow = x + (size_t)tok * H_DIM;
    unsigned short* xbrow = xbf + (size_t)tok * H_DIM;
    float acc[NE] = {};
    for (int h = l; h < H_DIM; h += 64) {
        float xv = xrow[h];
        xbrow[h] = f2bf(xv);
#pragma unroll
        for (int e = 0; e < NE; e++) acc[e] += xv * wr[h * NE + e];
    }
#pragma unroll
    for (int e = 0; e < NE; e++) {
        for (int off = 32; off; off >>= 1) acc[e] += __shfl_xor(acc[e], off);
    }
    if (l == 0) {
        int i1 = 0; float b1 = acc[0];
#pragma unroll
        for (int e = 1; e < NE; e++) if (acc[e] > b1) { b1 = acc[e]; i1 = e; }
        int i2 = -1; float b2 = -1e30f;
#pragma unroll
        for (int e = 0; e < NE; e++) if (e != i1 && acc[e] > b2) { b2 = acc[e]; i2 = e; }
        float w1 = 1.0f / (1.0f + __expf(b2 - b1));   // exact renormalized top-2
        top_i[tok * 2] = i1; top_i[tok * 2 + 1] = i2;
        top_w[tok * 2] = w1; top_w[tok * 2 + 1] = 1.0f - w1;
        atomicAdd(&counts[i1], 1); atomicAdd(&counts[i2], 1);
    }
}

// prefix + work-table: tile list of (expert, m-tile) pairs, 128 rows per tile
__global__ void prefix_kernel(const int* __restrict__ counts,
                              int* __restrict__ offsets, int* __restrict__ cursor,
                              int* __restrict__ wtab)
{
    if (threadIdx.x == 0 && blockIdx.x == 0) {
        int s = 0;
        for (int e = 0; e < NE; e++) { offsets[e] = s; cursor[e] = s; s += counts[e]; }
        offsets[NE] = s;
        int idx = 0;
        for (int e = 0; e < NE; e++) {
            int nt = (counts[e] + 127) >> 7;
            for (int mt = 0; mt < nt && idx < NTILE_MAX; ++mt) wtab[idx++] = (e << 16) | mt;
        }
        while (idx < NTILE_MAX) wtab[idx++] = -1;
    }
}

__global__ __launch_bounds__(256) void scatter_kernel(
    const int* __restrict__ top_i,
    int* __restrict__ cursor, int* __restrict__ pair_tok, int* __restrict__ inv_pos)
{
    int tok = blockIdx.x * 256 + threadIdx.x;
    if (tok < T_TOK) {
#pragma unroll
        for (int k = 0; k < 2; k++) {
            int e = top_i[tok * 2 + k];
            int pos = atomicAdd(&cursor[e], 1);
            pair_tok[pos] = tok;
            inv_pos[tok * 2 + k] = pos;
        }
    }
}

// ---------------- transpose+cvt generic: in[e][R][C] f32 -> out[e][C][R] bf16 ----------------
__global__ __launch_bounds__(256) void transpose_cvt_v2(
    const float* __restrict__ in, unsigned short* __restrict__ outp, int R, int C)
{
    __shared__ uint32_t tile[64][33];
    const int e = blockIdx.z;
    const float* inp = in + (size_t)e * R * C;
    unsigned short* oute = outp + (size_t)e * R * C;
    const int c0 = blockIdx.x * 64, r0 = blockIdx.y * 64;
    const int t = threadIdx.x;
#pragma unroll
    for (int i = 0; i < 8; ++i) {
        int lin = i * 256 + t;
        int r = lin >> 5, cp = lin & 31;
        float2 v = *(const float2*)&inp[(size_t)(r0 + r) * C + c0 + cp * 2];
        tile[r][cp] = (uint32_t)f2bf(v.x) | ((uint32_t)f2bf(v.y) << 16);
    }
    __syncthreads();
#pragma unroll
    for (int q = 0; q < 4; ++q) {
        int oc = (t >> 4) + q * 16;
        int j = t & 15;
        int cp = oc >> 1, sh = (oc & 1) * 16;
        ushort4 o;
        o.x = (unsigned short)(tile[j * 4 + 0][cp] >> sh);
        o.y = (unsigned short)(tile[j * 4 + 1][cp] >> sh);
        o.z = (unsigned short)(tile[j * 4 + 2][cp] >> sh);
        o.w = (unsigned short)(tile[j * 4 + 3][cp] >> sh);
        *(ushort4*)&oute[(size_t)(c0 + oc) * R + r0 + j * 4] = o;
    }
}

// gate+up in one launch: z<8 -> wg[e=z], z>=8 -> wu[e=z-8]; R=H, C=F
__global__ __launch_bounds__(256) void transpose_cvt_gu(
    const float* __restrict__ wg, const float* __restrict__ wu,
    unsigned short* __restrict__ wgT, unsigned short* __restrict__ wuT)
{
    __shared__ uint32_t tile[64][33];
    const int z = blockIdx.z;
    const int e = z & 7;
    const float* inp = (z < 8 ? wg : wu) + (size_t)e * H_DIM * F_DIM;
    unsigned short* oute = (z < 8 ? wgT : wuT) + (size_t)e * H_DIM * F_DIM;
    const int c0 = blockIdx.x * 64, r0 = blockIdx.y * 64;
    const int t = threadIdx.x;
#pragma unroll
    for (int i = 0; i < 8; ++i) {
        int lin = i * 256 + t;
        int r = lin >> 5, cp = lin & 31;
        float2 v = *(const float2*)&inp[(size_t)(r0 + r) * F_DIM + c0 + cp * 2];
        tile[r][cp] = (uint32_t)f2bf(v.x) | ((uint32_t)f2bf(v.y) << 16);
    }
    __syncthreads();
#pragma unroll
    for (int q = 0; q < 4; ++q) {
        int oc = (t >> 4) + q * 16;
        int j = t & 15;
        int cp = oc >> 1, sh = (oc & 1) * 16;
        ushort4 o;
        o.x = (unsigned short)(tile[j * 4 + 0][cp] >> sh);
        o.y = (unsigned short)(tile[j * 4 + 1][cp] >> sh);
        o.z = (unsigned short)(tile[j * 4 + 2][cp] >> sh);
        o.w = (unsigned short)(tile[j * 4 + 3][cp] >> sh);
        *(ushort4*)&oute[(size_t)(c0 + oc) * H_DIM + r0 + j * 4] = o;
    }
}

// ---------------- GEMM1: m97-style, 128 rows x 64 f (gate+up), BK=64, 32KB LDS ----------------
// grid: (x = m-tile [72], y = f-panel [44]) -> m fastest; 72%8==0 keeps each m-tile's
// f-blocks on one XCD (A-panel L2-resident).
__global__ __launch_bounds__(256, 4) void gemm1_kernel(
    const unsigned short* __restrict__ xbf,
    const unsigned short* __restrict__ wgT,
    const unsigned short* __restrict__ wuT,
    const int* __restrict__ pair_tok, const int* __restrict__ offsets,
    const int* __restrict__ wtab,
    unsigned short* __restrict__ Abuf)
{
    const int wv = wtab[blockIdx.x];
    if (wv < 0) return;
    const int e = wv >> 16;
    const int m0 = (wv & 0xFFFF) * 128;
    const int off = offsets[e], Ne = offsets[e + 1] - off;
    const int bn0 = blockIdx.y * 64;

    __shared__ unsigned short smem[16384];   // 32KB
    unsigned short* sA = smem;               // bytes [0, 16384)
    char* sG = (char*)smem + 16384;          // [16384, 24576)
    char* sU = (char*)smem + 24576;          // [24576, 32768)

    const int t = threadIdx.x, l = t & 63, w = t >> 6;
    const int llo = l & 15, lhi = l >> 4;
    const int wm = w >> 1, wn = w & 1;
    const int slr = l >> 3, slc = l & 7;     // staging: row-in-seg, chunk

    // staging sources: A = 16 segs (4/wave), G/U = 8 segs (2/wave). seg = 8 rows x 128B.
    const unsigned short* srcA[4];
#pragma unroll
    for (int i = 0; i < 4; ++i) {
        int s = w * 4 + i;
        int r = s * 8 + slr;
        int pr = m0 + r; if (pr > Ne - 1) pr = Ne - 1;
        srcA[i] = xbf + (size_t)pair_tok[off + pr] * H_DIM + (slc ^ (r & 7)) * 8;
    }
    const unsigned short* srcG[2];
    const unsigned short* srcU[2];
#pragma unroll
    for (int i = 0; i < 2; ++i) {
        int s = w * 2 + i;
        int fr = s * 8 + slr;
        srcG[i] = wgT + ((size_t)e * F_DIM + bn0 + fr) * H_DIM + (slc ^ (fr & 7)) * 8;
        srcU[i] = wuT + ((size_t)e * F_DIM + bn0 + fr) * H_DIM + (slc ^ (fr & 7)) * 8;
    }

    // fragment byte offsets
    int aoff[4][2], goff[2][2];
#pragma unroll
    for (int m = 0; m < 4; ++m) {
        int row = wm * 64 + m * 16 + llo;
#pragma unroll
        for (int kk = 0; kk < 2; ++kk)
            aoff[m][kk] = row * 128 + (((kk * 4 + lhi) ^ (row & 7)) * 16);
    }
#pragma unroll
    for (int n = 0; n < 2; ++n) {
        int g = wn * 32 + n * 16 + llo;
#pragma unroll
        for (int kk = 0; kk < 2; ++kk)
            goff[n][kk] = g * 128 + (((kk * 4 + lhi) ^ (g & 7)) * 16);
    }

    f32x4 accG[4][2] = {}, accU[4][2] = {};

    for (int k0 = 0; k0 < H_DIM; k0 += 64) {
        __syncthreads();
#pragma unroll
        for (int i = 0; i < 4; ++i)
            gload_lds16(srcA[i] + k0, (char*)sA + (w * 4 + i) * 1024);
#pragma unroll
        for (int i = 0; i < 2; ++i) {
            gload_lds16(srcG[i] + k0, sG + (w * 2 + i) * 1024);
            gload_lds16(srcU[i] + k0, sU + (w * 2 + i) * 1024);
        }
        asm volatile("s_waitcnt vmcnt(0)" ::: "memory");
        __syncthreads();

#pragma unroll
        for (int kk = 0; kk < 2; ++kk) {
            bf16x8 af[4], gf[2], uf[2];
#pragma unroll
            for (int m = 0; m < 4; ++m) af[m] = *(const bf16x8*)((const char*)sA + aoff[m][kk]);
#pragma unroll
            for (int n = 0; n < 2; ++n) {
                gf[n] = *(const bf16x8*)(sG + goff[n][kk]);
                uf[n] = *(const bf16x8*)(sU + goff[n][kk]);
            }
            __builtin_amdgcn_s_setprio(1);
#pragma unroll
            for (int m = 0; m < 4; ++m)
#pragma unroll
                for (int n = 0; n < 2; ++n) {
                    accG[m][n] = __builtin_amdgcn_mfma_f32_16x16x32_bf16(af[m], gf[n], accG[m][n], 0, 0, 0);
                    accU[m][n] = __builtin_amdgcn_mfma_f32_16x16x32_bf16(af[m], uf[n], accU[m][n], 0, 0, 0);
                }
            __builtin_amdgcn_s_setprio(0);
        }
    }

    // epilogue: silu(g)*u -> bf16. C/D: col=lane&15, row=(lane>>4)*4+reg
#pragma unroll
    for (int m = 0; m < 4; ++m) {
#pragma unroll
        for (int r = 0; r < 4; ++r) {
            int grow = m0 + wm * 64 + m * 16 + lhi * 4 + r;
            if (grow < Ne) {
                size_t p = (size_t)(off + grow);
#pragma unroll
                for (int n = 0; n < 2; ++n) {
                    float g = accG[m][n][r], u = accU[m][n][r];
                    float a = g / (1.0f + __expf(-g)) * u;
                    Abuf[p * F_DIM + bn0 + wn * 32 + n * 16 + llo] = f2bf(a);
                }
            }
        }
    }
}

// ---------------- GEMM2: m97-style, 128 x 128, BK=64, 32KB LDS, writes dbuf (no atomics) ----------------
// grid: (x = m-tile [72], y = h-panel [8])
__global__ __launch_bounds__(256, 4) void gemm2_kernel(
    const unsigned short* __restrict__ Abuf,
    const unsigned short* __restrict__ wdT,
    const int* __restrict__ offsets, const int* __restrict__ wtab,
    float* __restrict__ dbuf)
{
    const int wv = wtab[blockIdx.x];
    if (wv < 0) return;
    const int e = wv >> 16;
    const int m0 = (wv & 0xFFFF) * 128;
    const int off = offsets[e], Ne = offsets[e + 1] - off;
    const int bn0 = blockIdx.y * 128;

    __shared__ unsigned short smem[16384];   // 32KB: A 16KB | B 16KB
    unsigned short* sA = smem;
    char* sB = (char*)smem + 16384;

    const int t = threadIdx.x, l = t & 63, w = t >> 6;
    const int llo = l & 15, lhi = l >> 4;
    const int wm = w >> 1, wn = w & 1;
    const int slr = l >> 3, slc = l & 7;

    const unsigned short* srcA[4];
    const unsigned short* srcB[4];
#pragma unroll
    for (int i = 0; i < 4; ++i) {
        int s = w * 4 + i;
        int r = s * 8 + slr;
        int pr = m0 + r; if (pr > Ne - 1) pr = Ne - 1;
        srcA[i] = Abuf + (size_t)(off + pr) * F_DIM + (slc ^ (r & 7)) * 8;
        srcB[i] = wdT + ((size_t)e * H_DIM + bn0 + r) * F_DIM + (slc ^ (r & 7)) * 8;
    }

    int aoff[4][2], boff[4][2];
#pragma unroll
    for (int m = 0; m < 4; ++m) {
        int row = wm * 64 + m * 16 + llo;
        int brow = wn * 64 + m * 16 + llo;
#pragma unroll
        for (int kk = 0; kk < 2; ++kk) {
            aoff[m][kk] = row * 128 + (((kk * 4 + lhi) ^ (row & 7)) * 16);
            boff[m][kk] = brow * 128 + (((kk * 4 + lhi) ^ (brow & 7)) * 16);
        }
    }

    f32x4 acc[4][4] = {};

    for (int k0 = 0; k0 < F_DIM; k0 += 64) {
        __syncthreads();
#pragma unroll
        for (int i = 0; i < 4; ++i) {
            gload_lds16(srcA[i] + k0, (char*)sA + (w * 4 + i) * 1024);
            gload_lds16(srcB[i] + k0, sB + (w * 4 + i) * 1024);
        }
        asm volatile("s_waitcnt vmcnt(0)" ::: "memory");
        __syncthreads();

#pragma unroll
        for (int kk = 0; kk < 2; ++kk) {
            bf16x8 af[4], bfr[4];
#pragma unroll
            for (int m = 0; m < 4; ++m) {
                af[m]  = *(const bf16x8*)((const char*)sA + aoff[m][kk]);
                bfr[m] = *(const bf16x8*)(sB + boff[m][kk]);
            }
            __builtin_amdgcn_s_setprio(1);
#pragma unroll
            for (int m = 0; m < 4; ++m)
#pragma unroll
                for (int n = 0; n < 4; ++n)
                    acc[m][n] = __builtin_amdgcn_mfma_f32_16x16x32_bf16(af[m], bfr[n], acc[m][n], 0, 0, 0);
            __builtin_amdgcn_s_setprio(0);
        }
    }

    // epilogue: plain f32 stores to per-pair rows (combine kernel does the weighted sum)
#pragma unroll
    for (int m = 0; m < 4; ++m) {
#pragma unroll
        for (int r = 0; r < 4; ++r) {
            int grow = m0 + wm * 64 + m * 16 + lhi * 4 + r;
            if (grow < Ne) {
                size_t p = (size_t)(off + grow);
#pragma unroll
                for (int n = 0; n < 4; ++n)
                    dbuf[p * H_DIM + bn0 + wn * 64 + n * 16 + llo] = acc[m][n][r];
            }
        }
    }
}

// ---------------- combine: out[t] = w0*d[p0] + w1*d[p1] ----------------
__global__ __launch_bounds__(256) void combine_kernel(
    const float* __restrict__ dbuf, const int* __restrict__ inv_pos,
    const float* __restrict__ top_w, float* __restrict__ out)
{
    int tok = blockIdx.x;
    int p0 = inv_pos[tok * 2], p1 = inv_pos[tok * 2 + 1];
    float w0 = top_w[tok * 2], w1 = top_w[tok * 2 + 1];
    int c = threadIdx.x * 4;
    float4 a = *(const float4*)&dbuf[(size_t)p0 * H_DIM + c];
    float4 b = *(const float4*)&dbuf[(size_t)p1 * H_DIM + c];
    float4 o;
    o.x = w0 * a.x + w1 * b.x;
    o.y = w0 * a.y + w1 * b.y;
    o.z = w0 * a.z + w1 * b.z;
    o.w = w0 * a.w + w1 * b.w;
    *(float4*)&out[(size_t)tok * H_DIM + c] = o;
}

extern "C" void kernel_launch(void* const* d_in, const int* in_sizes, int n_in,
                              void* d_out, int out_size, void* d_ws, size_t ws_size,
                              hipStream_t stream)
{
    const float* x  = (const float*)d_in[0];
    const float* wr = (const float*)d_in[1];
    const float* wg = (const float*)d_in[2];
    const float* wu = (const float*)d_in[3];
    const float* wd = (const float*)d_in[4];
    float* out = (float*)d_out;

    char* ws = (char*)d_ws;
    const size_t WT = (size_t)NE * F_DIM * H_DIM * 2;            // 46,137,344 B
    unsigned short* wgT  = (unsigned short*)(ws);                // reused as wdT after gemm1
    unsigned short* wuT  = (unsigned short*)(ws + WT);           // reused as dbuf (f32, 33.5MB) after gemm1
    unsigned short* Abuf = (unsigned short*)(ws + 2 * WT);
    unsigned short* xbf  = (unsigned short*)(ws + 3 * WT);
    char* misc = ws + 3 * WT + (size_t)T_TOK * H_DIM * 2;
    int*   pair_tok = (int*)(misc);
    int*   top_i    = (int*)(misc + 32768);
    float* top_w    = (float*)(misc + 65536);
    int*   inv_pos  = (int*)(misc + 98304);
    int*   counts   = (int*)(misc + 131072);
    int*   offsets  = counts + 8;
    int*   cursor   = offsets + 9;
    int*   wtab     = cursor + 8;
    unsigned short* wdT = wgT;
    float* dbuf = (float*)wuT;

    hipMemsetAsync(counts, 0, 8 * sizeof(int), stream);

    transpose_cvt_gu<<<dim3(F_DIM / 64, H_DIM / 64, 16), 256, 0, stream>>>(wg, wu, wgT, wuT);
    router_kernel<<<T_TOK / 4, 256, 0, stream>>>(x, wr, xbf, top_i, top_w, counts);
    prefix_kernel<<<1, 64, 0, stream>>>(counts, offsets, cursor, wtab);
    scatter_kernel<<<T_TOK / 256, 256, 0, stream>>>(top_i, cursor, pair_tok, inv_pos);
    gemm1_kernel<<<dim3(NTILE_MAX, F_DIM / 64), 256, 0, stream>>>(xbf, wgT, wuT, pair_tok, offsets, wtab, Abuf);
    transpose_cvt_v2<<<dim3(H_DIM / 64, F_DIM / 64, NE), 256, 0, stream>>>(wd, wdT, F_DIM, H_DIM);
    gemm2_kernel<<<dim3(NTILE_MAX, H_DIM / 128), 256, 0, stream>>>(Abuf, wdT, offsets, wtab, dbuf);
    combine_kernel<<<T_TOK, 256, 0, stream>>>(dbuf, inv_pos, top_w, out);
}

// Round 6
// 406.687 us; speedup vs baseline: 1.0901x; 1.0901x over previous
//
#include <hip/hip_runtime.h>
#include <hip/hip_bf16.h>
#include <stdint.h>

#define T_TOK 4096
#define H_DIM 1024
#define F_DIM 2816
#define NE 8
#define NTILE_MAX 72   // >= sum_e ceil(Ne/128) worst case (64 + 7 partials)

using bf16x8 = __attribute__((ext_vector_type(8))) short;   // 8 bf16 in 4 VGPRs
using f32x4  = __attribute__((ext_vector_type(4))) float;   // MFMA accumulator

// RNE float -> bf16 bits (finite inputs only)
__device__ __forceinline__ unsigned short f2bf(float f) {
    union { float f; uint32_t u; } v; v.f = f;
    uint32_t r = v.u + 0x7FFFu + ((v.u >> 16) & 1u);
    return (unsigned short)(r >> 16);
}

// async global->LDS, 16B per lane. lds dest: wave-uniform base + lane*16.
__device__ __forceinline__ void gload_lds16(const void* gsrc, void* lds) {
    __builtin_amdgcn_global_load_lds(
        (const __attribute__((address_space(1))) uint32_t*)gsrc,
        (__attribute__((address_space(3))) uint32_t*)lds, 16, 0, 0);
}

// ---------------- router: one wave per token; also emits xbf (bf16 cast of x) ----------------
__global__ __launch_bounds__(256) void router_kernel(
    const float* __restrict__ x, const float* __restrict__ wr,
    unsigned short* __restrict__ xbf,
    int* __restrict__ top_i, float* __restrict__ top_w, int* __restrict__ counts)
{
    const int w = threadIdx.x >> 6, l = threadIdx.x & 63;
    const int tok = blockIdx.x * 4 + w;
    const float* xrow = x + (size_t)tok * H_DIM;
    unsigned short* xbrow = xbf + (size_t)tok * H_DIM;
    float acc[NE] = {};
    for (int h = l; h < H_DIM; h += 64) {
        float xv = xrow[h];
        xbrow[h] = f2bf(xv);
#pragma unroll
        for (int e = 0; e < NE; e++) acc[e] += xv * wr[h * NE + e];
    }
#pragma unroll
    for (int e = 0; e < NE; e++) {
        for (int off = 32; off; off >>= 1) acc[e] += __shfl_xor(acc[e], off);
    }
    if (l == 0) {
        int i1 = 0; float b1 = acc[0];
#pragma unroll
        for (int e = 1; e < NE; e++) if (acc[e] > b1) { b1 = acc[e]; i1 = e; }
        int i2 = -1; float b2 = -1e30f;
#pragma unroll
        for (int e = 0; e < NE; e++) if (e != i1 && acc[e] > b2) { b2 = acc[e]; i2 = e; }
        float w1 = 1.0f / (1.0f + __expf(b2 - b1));   // exact renormalized top-2
        top_i[tok * 2] = i1; top_i[tok * 2 + 1] = i2;
        top_w[tok * 2] = w1; top_w[tok * 2 + 1] = 1.0f - w1;
        atomicAdd(&counts[i1], 1); atomicAdd(&counts[i2], 1);
    }
}

// prefix + work-table: tile list of (expert, m-tile) pairs, 128 rows per tile
__global__ void prefix_kernel(const int* __restrict__ counts,
                              int* __restrict__ offsets, int* __restrict__ cursor,
                              int* __restrict__ wtab)
{
    if (threadIdx.x == 0 && blockIdx.x == 0) {
        int s = 0;
        for (int e = 0; e < NE; e++) { offsets[e] = s; cursor[e] = s; s += counts[e]; }
        offsets[NE] = s;
        int idx = 0;
        for (int e = 0; e < NE; e++) {
            int nt = (counts[e] + 127) >> 7;
            for (int mt = 0; mt < nt && idx < NTILE_MAX; ++mt) wtab[idx++] = (e << 16) | mt;
        }
        while (idx < NTILE_MAX) wtab[idx++] = -1;
    }
}

__global__ __launch_bounds__(256) void scatter_kernel(
    const int* __restrict__ top_i,
    int* __restrict__ cursor, int* __restrict__ pair_tok, int* __restrict__ inv_pos)
{
    int tok = blockIdx.x * 256 + threadIdx.x;
    if (tok < T_TOK) {
#pragma unroll
        for (int k = 0; k < 2; k++) {
            int e = top_i[tok * 2 + k];
            int pos = atomicAdd(&cursor[e], 1);
            pair_tok[pos] = tok;
            inv_pos[tok * 2 + k] = pos;
        }
    }
}

// ---------------- transpose+cvt generic: in[e][R][C] f32 -> out[e][C][R] bf16 ----------------
__global__ __launch_bounds__(256) void transpose_cvt_v2(
    const float* __restrict__ in, unsigned short* __restrict__ outp, int R, int C)
{
    __shared__ uint32_t tile[64][33];
    const int e = blockIdx.z;
    const float* inp = in + (size_t)e * R * C;
    unsigned short* oute = outp + (size_t)e * R * C;
    const int c0 = blockIdx.x * 64, r0 = blockIdx.y * 64;
    const int t = threadIdx.x;
#pragma unroll
    for (int i = 0; i < 8; ++i) {
        int lin = i * 256 + t;
        int r = lin >> 5, cp = lin & 31;
        float2 v = *(const float2*)&inp[(size_t)(r0 + r) * C + c0 + cp * 2];
        tile[r][cp] = (uint32_t)f2bf(v.x) | ((uint32_t)f2bf(v.y) << 16);
    }
    __syncthreads();
#pragma unroll
    for (int q = 0; q < 4; ++q) {
        int oc = (t >> 4) + q * 16;
        int j = t & 15;
        int cp = oc >> 1, sh = (oc & 1) * 16;
        ushort4 o;
        o.x = (unsigned short)(tile[j * 4 + 0][cp] >> sh);
        o.y = (unsigned short)(tile[j * 4 + 1][cp] >> sh);
        o.z = (unsigned short)(tile[j * 4 + 2][cp] >> sh);
        o.w = (unsigned short)(tile[j * 4 + 3][cp] >> sh);
        *(ushort4*)&oute[(size_t)(c0 + oc) * R + r0 + j * 4] = o;
    }
}

// gate+up in one launch: z<8 -> wg[e=z], z>=8 -> wu[e=z-8]; R=H, C=F
__global__ __launch_bounds__(256) void transpose_cvt_gu(
    const float* __restrict__ wg, const float* __restrict__ wu,
    unsigned short* __restrict__ wgT, unsigned short* __restrict__ wuT)
{
    __shared__ uint32_t tile[64][33];
    const int z = blockIdx.z;
    const int e = z & 7;
    const float* inp = (z < 8 ? wg : wu) + (size_t)e * H_DIM * F_DIM;
    unsigned short* oute = (z < 8 ? wgT : wuT) + (size_t)e * H_DIM * F_DIM;
    const int c0 = blockIdx.x * 64, r0 = blockIdx.y * 64;
    const int t = threadIdx.x;
#pragma unroll
    for (int i = 0; i < 8; ++i) {
        int lin = i * 256 + t;
        int r = lin >> 5, cp = lin & 31;
        float2 v = *(const float2*)&inp[(size_t)(r0 + r) * F_DIM + c0 + cp * 2];
        tile[r][cp] = (uint32_t)f2bf(v.x) | ((uint32_t)f2bf(v.y) << 16);
    }
    __syncthreads();
#pragma unroll
    for (int q = 0; q < 4; ++q) {
        int oc = (t >> 4) + q * 16;
        int j = t & 15;
        int cp = oc >> 1, sh = (oc & 1) * 16;
        ushort4 o;
        o.x = (unsigned short)(tile[j * 4 + 0][cp] >> sh);
        o.y = (unsigned short)(tile[j * 4 + 1][cp] >> sh);
        o.z = (unsigned short)(tile[j * 4 + 2][cp] >> sh);
        o.w = (unsigned short)(tile[j * 4 + 3][cp] >> sh);
        *(ushort4*)&oute[(size_t)(c0 + oc) * H_DIM + r0 + j * 4] = o;
    }
}

// ---------------- GEMM1: m97-style, 128 rows x 64 f (gate+up), BK=64, 32KB LDS ----------------
// grid: (x = f-panel [44] FAST, y = m-tile [72]) -> consecutive blocks share the A-panel (L2-hot);
// the 92MB weight stream lives in LLC across m-tiles. (Round-4 ordering, 111 us.)
__global__ __launch_bounds__(256, 4) void gemm1_kernel(
    const unsigned short* __restrict__ xbf,
    const unsigned short* __restrict__ wgT,
    const unsigned short* __restrict__ wuT,
    const int* __restrict__ pair_tok, const int* __restrict__ offsets,
    const int* __restrict__ wtab,
    unsigned short* __restrict__ Abuf)
{
    const int wv = wtab[blockIdx.y];
    if (wv < 0) return;
    const int e = wv >> 16;
    const int m0 = (wv & 0xFFFF) * 128;
    const int off = offsets[e], Ne = offsets[e + 1] - off;
    const int bn0 = blockIdx.x * 64;

    __shared__ unsigned short smem[16384];   // 32KB
    unsigned short* sA = smem;               // bytes [0, 16384)
    char* sG = (char*)smem + 16384;          // [16384, 24576)
    char* sU = (char*)smem + 24576;          // [24576, 32768)

    const int t = threadIdx.x, l = t & 63, w = t >> 6;
    const int llo = l & 15, lhi = l >> 4;
    const int wm = w >> 1, wn = w & 1;
    const int slr = l >> 3, slc = l & 7;     // staging: row-in-seg, chunk

    // staging sources: A = 16 segs (4/wave), G/U = 8 segs (2/wave). seg = 8 rows x 128B.
    const unsigned short* srcA[4];
#pragma unroll
    for (int i = 0; i < 4; ++i) {
        int s = w * 4 + i;
        int r = s * 8 + slr;
        int pr = m0 + r; if (pr > Ne - 1) pr = Ne - 1;
        srcA[i] = xbf + (size_t)pair_tok[off + pr] * H_DIM + (slc ^ (r & 7)) * 8;
    }
    const unsigned short* srcG[2];
    const unsigned short* srcU[2];
#pragma unroll
    for (int i = 0; i < 2; ++i) {
        int s = w * 2 + i;
        int fr = s * 8 + slr;
        srcG[i] = wgT + ((size_t)e * F_DIM + bn0 + fr) * H_DIM + (slc ^ (fr & 7)) * 8;
        srcU[i] = wuT + ((size_t)e * F_DIM + bn0 + fr) * H_DIM + (slc ^ (fr & 7)) * 8;
    }

    // fragment byte offsets
    int aoff[4][2], goff[2][2];
#pragma unroll
    for (int m = 0; m < 4; ++m) {
        int row = wm * 64 + m * 16 + llo;
#pragma unroll
        for (int kk = 0; kk < 2; ++kk)
            aoff[m][kk] = row * 128 + (((kk * 4 + lhi) ^ (row & 7)) * 16);
    }
#pragma unroll
    for (int n = 0; n < 2; ++n) {
        int g = wn * 32 + n * 16 + llo;
#pragma unroll
        for (int kk = 0; kk < 2; ++kk)
            goff[n][kk] = g * 128 + (((kk * 4 + lhi) ^ (g & 7)) * 16);
    }

    f32x4 accG[4][2] = {}, accU[4][2] = {};

    for (int k0 = 0; k0 < H_DIM; k0 += 64) {
        __syncthreads();
#pragma unroll
        for (int i = 0; i < 4; ++i)
            gload_lds16(srcA[i] + k0, (char*)sA + (w * 4 + i) * 1024);
#pragma unroll
        for (int i = 0; i < 2; ++i) {
            gload_lds16(srcG[i] + k0, sG + (w * 2 + i) * 1024);
            gload_lds16(srcU[i] + k0, sU + (w * 2 + i) * 1024);
        }
        asm volatile("s_waitcnt vmcnt(0)" ::: "memory");
        __syncthreads();

#pragma unroll
        for (int kk = 0; kk < 2; ++kk) {
            bf16x8 af[4], gf[2], uf[2];
#pragma unroll
            for (int m = 0; m < 4; ++m) af[m] = *(const bf16x8*)((const char*)sA + aoff[m][kk]);
#pragma unroll
            for (int n = 0; n < 2; ++n) {
                gf[n] = *(const bf16x8*)(sG + goff[n][kk]);
                uf[n] = *(const bf16x8*)(sU + goff[n][kk]);
            }
            __builtin_amdgcn_s_setprio(1);
#pragma unroll
            for (int m = 0; m < 4; ++m)
#pragma unroll
                for (int n = 0; n < 2; ++n) {
                    accG[m][n] = __builtin_amdgcn_mfma_f32_16x16x32_bf16(af[m], gf[n], accG[m][n], 0, 0, 0);
                    accU[m][n] = __builtin_amdgcn_mfma_f32_16x16x32_bf16(af[m], uf[n], accU[m][n], 0, 0, 0);
                }
            __builtin_amdgcn_s_setprio(0);
        }
    }

    // epilogue: silu(g)*u -> bf16. C/D: col=lane&15, row=(lane>>4)*4+reg
#pragma unroll
    for (int m = 0; m < 4; ++m) {
#pragma unroll
        for (int r = 0; r < 4; ++r) {
            int grow = m0 + wm * 64 + m * 16 + lhi * 4 + r;
            if (grow < Ne) {
                size_t p = (size_t)(off + grow);
#pragma unroll
                for (int n = 0; n < 2; ++n) {
                    float g = accG[m][n][r], u = accU[m][n][r];
                    float a = g / (1.0f + __expf(-g)) * u;
                    Abuf[p * F_DIM + bn0 + wn * 32 + n * 16 + llo] = f2bf(a);
                }
            }
        }
    }
}

// ---------------- GEMM2: m97-style, 128 x 128, BK=64, 32KB LDS, writes dbuf (no atomics) ----------------
// grid: (x = h-panel [8] FAST, y = m-tile [72]) -- round-4 ordering
__global__ __launch_bounds__(256, 4) void gemm2_kernel(
    const unsigned short* __restrict__ Abuf,
    const unsigned short* __restrict__ wdT,
    const int* __restrict__ offsets, const int* __restrict__ wtab,
    float* __restrict__ dbuf)
{
    const int wv = wtab[blockIdx.y];
    if (wv < 0) return;
    const int e = wv >> 16;
    const int m0 = (wv & 0xFFFF) * 128;
    const int off = offsets[e], Ne = offsets[e + 1] - off;
    const int bn0 = blockIdx.x * 128;

    __shared__ unsigned short smem[16384];   // 32KB: A 16KB | B 16KB
    unsigned short* sA = smem;
    char* sB = (char*)smem + 16384;

    const int t = threadIdx.x, l = t & 63, w = t >> 6;
    const int llo = l & 15, lhi = l >> 4;
    const int wm = w >> 1, wn = w & 1;
    const int slr = l >> 3, slc = l & 7;

    const unsigned short* srcA[4];
    const unsigned short* srcB[4];
#pragma unroll
    for (int i = 0; i < 4; ++i) {
        int s = w * 4 + i;
        int r = s * 8 + slr;
        int pr = m0 + r; if (pr > Ne - 1) pr = Ne - 1;
        srcA[i] = Abuf + (size_t)(off + pr) * F_DIM + (slc ^ (r & 7)) * 8;
        srcB[i] = wdT + ((size_t)e * H_DIM + bn0 + r) * F_DIM + (slc ^ (r & 7)) * 8;
    }

    int aoff[4][2], boff[4][2];
#pragma unroll
    for (int m = 0; m < 4; ++m) {
        int row = wm * 64 + m * 16 + llo;
        int brow = wn * 64 + m * 16 + llo;
#pragma unroll
        for (int kk = 0; kk < 2; ++kk) {
            aoff[m][kk] = row * 128 + (((kk * 4 + lhi) ^ (row & 7)) * 16);
            boff[m][kk] = brow * 128 + (((kk * 4 + lhi) ^ (brow & 7)) * 16);
        }
    }

    f32x4 acc[4][4] = {};

    for (int k0 = 0; k0 < F_DIM; k0 += 64) {
        __syncthreads();
#pragma unroll
        for (int i = 0; i < 4; ++i) {
            gload_lds16(srcA[i] + k0, (char*)sA + (w * 4 + i) * 1024);
            gload_lds16(srcB[i] + k0, sB + (w * 4 + i) * 1024);
        }
        asm volatile("s_waitcnt vmcnt(0)" ::: "memory");
        __syncthreads();

#pragma unroll
        for (int kk = 0; kk < 2; ++kk) {
            bf16x8 af[4], bfr[4];
#pragma unroll
            for (int m = 0; m < 4; ++m) {
                af[m]  = *(const bf16x8*)((const char*)sA + aoff[m][kk]);
                bfr[m] = *(const bf16x8*)(sB + boff[m][kk]);
            }
            __builtin_amdgcn_s_setprio(1);
#pragma unroll
            for (int m = 0; m < 4; ++m)
#pragma unroll
                for (int n = 0; n < 4; ++n)
                    acc[m][n] = __builtin_amdgcn_mfma_f32_16x16x32_bf16(af[m], bfr[n], acc[m][n], 0, 0, 0);
            __builtin_amdgcn_s_setprio(0);
        }
    }

    // epilogue: plain f32 stores to per-pair rows (combine kernel does the weighted sum)
#pragma unroll
    for (int m = 0; m < 4; ++m) {
#pragma unroll
        for (int r = 0; r < 4; ++r) {
            int grow = m0 + wm * 64 + m * 16 + lhi * 4 + r;
            if (grow < Ne) {
                size_t p = (size_t)(off + grow);
#pragma unroll
                for (int n = 0; n < 4; ++n)
                    dbuf[p * H_DIM + bn0 + wn * 64 + n * 16 + llo] = acc[m][n][r];
            }
        }
    }
}

// ---------------- combine: out[t] = w0*d[p0] + w1*d[p1] ----------------
__global__ __launch_bounds__(256) void combine_kernel(
    const float* __restrict__ dbuf, const int* __restrict__ inv_pos,
    const float* __restrict__ top_w, float* __restrict__ out)
{
    int tok = blockIdx.x;
    int p0 = inv_pos[tok * 2], p1 = inv_pos[tok * 2 + 1];
    float w0 = top_w[tok * 2], w1 = top_w[tok * 2 + 1];
    int c = threadIdx.x * 4;
    float4 a = *(const float4*)&dbuf[(size_t)p0 * H_DIM + c];
    float4 b = *(const float4*)&dbuf[(size_t)p1 * H_DIM + c];
    float4 o;
    o.x = w0 * a.x + w1 * b.x;
    o.y = w0 * a.y + w1 * b.y;
    o.z = w0 * a.z + w1 * b.z;
    o.w = w0 * a.w + w1 * b.w;
    *(float4*)&out[(size_t)tok * H_DIM + c] = o;
}

extern "C" void kernel_launch(void* const* d_in, const int* in_sizes, int n_in,
                              void* d_out, int out_size, void* d_ws, size_t ws_size,
                              hipStream_t stream)
{
    const float* x  = (const float*)d_in[0];
    const float* wr = (const float*)d_in[1];
    const float* wg = (const float*)d_in[2];
    const float* wu = (const float*)d_in[3];
    const float* wd = (const float*)d_in[4];
    float* out = (float*)d_out;

    char* ws = (char*)d_ws;
    const size_t WT = (size_t)NE * F_DIM * H_DIM * 2;            // 46,137,344 B
    unsigned short* wgT  = (unsigned short*)(ws);                // reused as wdT after gemm1
    unsigned short* wuT  = (unsigned short*)(ws + WT);           // reused as dbuf (f32, 33.5MB) after gemm1
    unsigned short* Abuf = (unsigned short*)(ws + 2 * WT);
    unsigned short* xbf  = (unsigned short*)(ws + 3 * WT);
    char* misc = ws + 3 * WT + (size_t)T_TOK * H_DIM * 2;
    int*   pair_tok = (int*)(misc);
    int*   top_i    = (int*)(misc + 32768);
    float* top_w    = (float*)(misc + 65536);
    int*   inv_pos  = (int*)(misc + 98304);
    int*   counts   = (int*)(misc + 131072);
    int*   offsets  = counts + 8;
    int*   cursor   = offsets + 9;
    int*   wtab     = cursor + 8;
    unsigned short* wdT = wgT;
    float* dbuf = (float*)wuT;

    hipMemsetAsync(counts, 0, 8 * sizeof(int), stream);

    transpose_cvt_gu<<<dim3(F_DIM / 64, H_DIM / 64, 16), 256, 0, stream>>>(wg, wu, wgT, wuT);
    router_kernel<<<T_TOK / 4, 256, 0, stream>>>(x, wr, xbf, top_i, top_w, counts);
    prefix_kernel<<<1, 64, 0, stream>>>(counts, offsets, cursor, wtab);
    scatter_kernel<<<T_TOK / 256, 256, 0, stream>>>(top_i, cursor, pair_tok, inv_pos);
    gemm1_kernel<<<dim3(F_DIM / 64, NTILE_MAX), 256, 0, stream>>>(xbf, wgT, wuT, pair_tok, offsets, wtab, Abuf);
    transpose_cvt_v2<<<dim3(H_DIM / 64, F_DIM / 64, NE), 256, 0, stream>>>(wd, wdT, F_DIM, H_DIM);
    gemm2_kernel<<<dim3(H_DIM / 128, NTILE_MAX), 256, 0, stream>>>(Abuf, wdT, offsets, wtab, dbuf);
    combine_kernel<<<T_TOK, 256, 0, stream>>>(dbuf, inv_pos, top_w, out);
}

// Round 7
// 376.464 us; speedup vs baseline: 1.1776x; 1.0803x over previous
//
#include <hip/hip_runtime.h>
#include <hip/hip_bf16.h>
#include <stdint.h>

#define T_TOK 4096
#define H_DIM 1024
#define F_DIM 2816
#define NE 8
#define NTILE_MAX 72   // >= sum_e ceil(Ne/128) worst case (64 + 7 partials)

using bf16x8 = __attribute__((ext_vector_type(8))) short;   // 8 bf16 in 4 VGPRs
using f32x4  = __attribute__((ext_vector_type(4))) float;   // MFMA accumulator

// RNE float -> bf16 bits (finite inputs only)
__device__ __forceinline__ unsigned short f2bf(float f) {
    union { float f; uint32_t u; } v; v.f = f;
    uint32_t r = v.u + 0x7FFFu + ((v.u >> 16) & 1u);
    return (unsigned short)(r >> 16);
}

// async global->LDS, 16B per lane. lds dest: wave-uniform base + lane*16.
__device__ __forceinline__ void gload_lds16(const void* gsrc, void* lds) {
    __builtin_amdgcn_global_load_lds(
        (const __attribute__((address_space(1))) uint32_t*)gsrc,
        (__attribute__((address_space(3))) uint32_t*)lds, 16, 0, 0);
}

// ---------------- router: one wave per token; also emits xbf (bf16 cast of x) ----------------
__global__ __launch_bounds__(256) void router_kernel(
    const float* __restrict__ x, const float* __restrict__ wr,
    unsigned short* __restrict__ xbf,
    int* __restrict__ top_i, float* __restrict__ top_w, int* __restrict__ counts)
{
    const int w = threadIdx.x >> 6, l = threadIdx.x & 63;
    const int tok = blockIdx.x * 4 + w;
    const float* xrow = x + (size_t)tok * H_DIM;
    unsigned short* xbrow = xbf + (size_t)tok * H_DIM;
    float acc[NE] = {};
    for (int h = l; h < H_DIM; h += 64) {
        float xv = xrow[h];
        xbrow[h] = f2bf(xv);
#pragma unroll
        for (int e = 0; e < NE; e++) acc[e] += xv * wr[h * NE + e];
    }
#pragma unroll
    for (int e = 0; e < NE; e++) {
        for (int off = 32; off; off >>= 1) acc[e] += __shfl_xor(acc[e], off);
    }
    if (l == 0) {
        int i1 = 0; float b1 = acc[0];
#pragma unroll
        for (int e = 1; e < NE; e++) if (acc[e] > b1) { b1 = acc[e]; i1 = e; }
        int i2 = -1; float b2 = -1e30f;
#pragma unroll
        for (int e = 0; e < NE; e++) if (e != i1 && acc[e] > b2) { b2 = acc[e]; i2 = e; }
        float w1 = 1.0f / (1.0f + __expf(b2 - b1));   // exact renormalized top-2
        top_i[tok * 2] = i1; top_i[tok * 2 + 1] = i2;
        top_w[tok * 2] = w1; top_w[tok * 2 + 1] = 1.0f - w1;
        atomicAdd(&counts[i1], 1); atomicAdd(&counts[i2], 1);
    }
}

// ---------------- fused prefix + work-table + scatter (single block) ----------------
__global__ __launch_bounds__(256) void prefix_scatter_kernel(
    const int* __restrict__ counts, const int* __restrict__ top_i,
    int* __restrict__ offsets, int* __restrict__ wtab,
    int* __restrict__ pair_tok, int* __restrict__ inv_pos)
{
    __shared__ int scur[NE];
    if (threadIdx.x == 0) {
        int s = 0;
        for (int e = 0; e < NE; e++) { offsets[e] = s; scur[e] = s; s += counts[e]; }
        offsets[NE] = s;
        int idx = 0;
        for (int e = 0; e < NE; e++) {
            int nt = (counts[e] + 127) >> 7;
            for (int mt = 0; mt < nt && idx < NTILE_MAX; ++mt) wtab[idx++] = (e << 16) | mt;
        }
        while (idx < NTILE_MAX) wtab[idx++] = -1;
    }
    __syncthreads();
    for (int tok = threadIdx.x; tok < T_TOK; tok += 256) {
#pragma unroll
        for (int k = 0; k < 2; k++) {
            int e = top_i[tok * 2 + k];
            int pos = atomicAdd(&scur[e], 1);
            pair_tok[pos] = tok;
            inv_pos[tok * 2 + k] = pos;
        }
    }
}

// ---------------- transpose+cvt v3: in[R][C] f32 -> out[C][R] bf16, 64x64 tile ----------------
// float4 loads (16B/lane), uint4 stores (16B/lane). LDS conflicts <= 2-way (free).
__device__ __forceinline__ void transpose_tile_v3(
    const float* __restrict__ inp, unsigned short* __restrict__ oute,
    int R, int C, int r0, int c0, int t)
{
    __shared__ uint32_t tile[64][33];
#pragma unroll
    for (int p = 0; p < 4; ++p) {
        int r = p * 16 + (t >> 4);
        float4 v = *(const float4*)&inp[(size_t)(r0 + r) * C + c0 + (t & 15) * 4];
        tile[r][(t & 15) * 2]     = (uint32_t)f2bf(v.x) | ((uint32_t)f2bf(v.y) << 16);
        tile[r][(t & 15) * 2 + 1] = (uint32_t)f2bf(v.z) | ((uint32_t)f2bf(v.w) << 16);
    }
    __syncthreads();
#pragma unroll
    for (int p = 0; p < 2; ++p) {
        int oc = p * 32 + (t >> 3);
        int rb = (t & 7) * 8;
        int cp = oc >> 1, sh = (oc & 1) * 16;
        unsigned short u[8];
#pragma unroll
        for (int i = 0; i < 8; ++i) u[i] = (unsigned short)(tile[rb + i][cp] >> sh);
        uint4 o;
        o.x = (uint32_t)u[0] | ((uint32_t)u[1] << 16);
        o.y = (uint32_t)u[2] | ((uint32_t)u[3] << 16);
        o.z = (uint32_t)u[4] | ((uint32_t)u[5] << 16);
        o.w = (uint32_t)u[6] | ((uint32_t)u[7] << 16);
        *(uint4*)&oute[(size_t)(c0 + oc) * R + r0 + rb] = o;
    }
}

// generic: in[e][R][C] -> out[e][C][R]
__global__ __launch_bounds__(256) void transpose_cvt_v3(
    const float* __restrict__ in, unsigned short* __restrict__ outp, int R, int C)
{
    const int e = blockIdx.z;
    transpose_tile_v3(in + (size_t)e * R * C, outp + (size_t)e * R * C,
                      R, C, blockIdx.y * 64, blockIdx.x * 64, threadIdx.x);
}

// gate+up fused: z<8 -> wg[e=z], z>=8 -> wu[e=z-8]; R=H, C=F
__global__ __launch_bounds__(256) void transpose_cvt_gu3(
    const float* __restrict__ wg, const float* __restrict__ wu,
    unsigned short* __restrict__ wgT, unsigned short* __restrict__ wuT)
{
    const int z = blockIdx.z;
    const int e = z & 7;
    const float* inp = (z < 8 ? wg : wu) + (size_t)e * H_DIM * F_DIM;
    unsigned short* oute = (z < 8 ? wgT : wuT) + (size_t)e * H_DIM * F_DIM;
    transpose_tile_v3(inp, oute, H_DIM, F_DIM,
                      blockIdx.y * 64, blockIdx.x * 64, threadIdx.x);
}

// ---------------- GEMM1: m97-style, 128 rows x 64 f (gate+up), BK=64, 32KB LDS ----------------
// grid: (x = f-panel [44] FAST, y = m-tile [72]) -> consecutive blocks share the A-panel (L2-hot)
__global__ __launch_bounds__(256, 4) void gemm1_kernel(
    const unsigned short* __restrict__ xbf,
    const unsigned short* __restrict__ wgT,
    const unsigned short* __restrict__ wuT,
    const int* __restrict__ pair_tok, const int* __restrict__ offsets,
    const int* __restrict__ wtab,
    unsigned short* __restrict__ Abuf)
{
    const int wv = wtab[blockIdx.y];
    if (wv < 0) return;
    const int e = wv >> 16;
    const int m0 = (wv & 0xFFFF) * 128;
    const int off = offsets[e], Ne = offsets[e + 1] - off;
    const int bn0 = blockIdx.x * 64;

    __shared__ unsigned short smem[16384];   // 32KB
    unsigned short* sA = smem;               // bytes [0, 16384)
    char* sG = (char*)smem + 16384;          // [16384, 24576)
    char* sU = (char*)smem + 24576;          // [24576, 32768)

    const int t = threadIdx.x, l = t & 63, w = t >> 6;
    const int llo = l & 15, lhi = l >> 4;
    const int wm = w >> 1, wn = w & 1;
    const int slr = l >> 3, slc = l & 7;     // staging: row-in-seg, chunk

    const unsigned short* srcA[4];
#pragma unroll
    for (int i = 0; i < 4; ++i) {
        int s = w * 4 + i;
        int r = s * 8 + slr;
        int pr = m0 + r; if (pr > Ne - 1) pr = Ne - 1;
        srcA[i] = xbf + (size_t)pair_tok[off + pr] * H_DIM + (slc ^ (r & 7)) * 8;
    }
    const unsigned short* srcG[2];
    const unsigned short* srcU[2];
#pragma unroll
    for (int i = 0; i < 2; ++i) {
        int s = w * 2 + i;
        int fr = s * 8 + slr;
        srcG[i] = wgT + ((size_t)e * F_DIM + bn0 + fr) * H_DIM + (slc ^ (fr & 7)) * 8;
        srcU[i] = wuT + ((size_t)e * F_DIM + bn0 + fr) * H_DIM + (slc ^ (fr & 7)) * 8;
    }

    int aoff[4][2], goff[2][2];
#pragma unroll
    for (int m = 0; m < 4; ++m) {
        int row = wm * 64 + m * 16 + llo;
#pragma unroll
        for (int kk = 0; kk < 2; ++kk)
            aoff[m][kk] = row * 128 + (((kk * 4 + lhi) ^ (row & 7)) * 16);
    }
#pragma unroll
    for (int n = 0; n < 2; ++n) {
        int g = wn * 32 + n * 16 + llo;
#pragma unroll
        for (int kk = 0; kk < 2; ++kk)
            goff[n][kk] = g * 128 + (((kk * 4 + lhi) ^ (g & 7)) * 16);
    }

    f32x4 accG[4][2] = {}, accU[4][2] = {};

    for (int k0 = 0; k0 < H_DIM; k0 += 64) {
        __syncthreads();
#pragma unroll
        for (int i = 0; i < 4; ++i)
            gload_lds16(srcA[i] + k0, (char*)sA + (w * 4 + i) * 1024);
#pragma unroll
        for (int i = 0; i < 2; ++i) {
            gload_lds16(srcG[i] + k0, sG + (w * 2 + i) * 1024);
            gload_lds16(srcU[i] + k0, sU + (w * 2 + i) * 1024);
        }
        asm volatile("s_waitcnt vmcnt(0)" ::: "memory");
        __syncthreads();

#pragma unroll
        for (int kk = 0; kk < 2; ++kk) {
            bf16x8 af[4], gf[2], uf[2];
#pragma unroll
            for (int m = 0; m < 4; ++m) af[m] = *(const bf16x8*)((const char*)sA + aoff[m][kk]);
#pragma unroll
            for (int n = 0; n < 2; ++n) {
                gf[n] = *(const bf16x8*)(sG + goff[n][kk]);
                uf[n] = *(const bf16x8*)(sU + goff[n][kk]);
            }
            __builtin_amdgcn_s_setprio(1);
#pragma unroll
            for (int m = 0; m < 4; ++m)
#pragma unroll
                for (int n = 0; n < 2; ++n) {
                    accG[m][n] = __builtin_amdgcn_mfma_f32_16x16x32_bf16(af[m], gf[n], accG[m][n], 0, 0, 0);
                    accU[m][n] = __builtin_amdgcn_mfma_f32_16x16x32_bf16(af[m], uf[n], accU[m][n], 0, 0, 0);
                }
            __builtin_amdgcn_s_setprio(0);
        }
    }

    // epilogue: silu(g)*u -> bf16. C/D: col=lane&15, row=(lane>>4)*4+reg
#pragma unroll
    for (int m = 0; m < 4; ++m) {
#pragma unroll
        for (int r = 0; r < 4; ++r) {
            int grow = m0 + wm * 64 + m * 16 + lhi * 4 + r;
            if (grow < Ne) {
                size_t p = (size_t)(off + grow);
#pragma unroll
                for (int n = 0; n < 2; ++n) {
                    float g = accG[m][n][r], u = accU[m][n][r];
                    float a = g / (1.0f + __expf(-g)) * u;
                    Abuf[p * F_DIM + bn0 + wn * 32 + n * 16 + llo] = f2bf(a);
                }
            }
        }
    }
}

// ---------------- GEMM2: m97-style, 128 x 128, BK=64, 32KB LDS, writes bf16 dbuf ----------------
// grid: (x = h-panel [8] FAST, y = m-tile [72])
__global__ __launch_bounds__(256, 4) void gemm2_kernel(
    const unsigned short* __restrict__ Abuf,
    const unsigned short* __restrict__ wdT,
    const int* __restrict__ offsets, const int* __restrict__ wtab,
    unsigned short* __restrict__ dbuf)
{
    const int wv = wtab[blockIdx.y];
    if (wv < 0) return;
    const int e = wv >> 16;
    const int m0 = (wv & 0xFFFF) * 128;
    const int off = offsets[e], Ne = offsets[e + 1] - off;
    const int bn0 = blockIdx.x * 128;

    __shared__ unsigned short smem[16384];   // 32KB: A 16KB | B 16KB
    unsigned short* sA = smem;
    char* sB = (char*)smem + 16384;

    const int t = threadIdx.x, l = t & 63, w = t >> 6;
    const int llo = l & 15, lhi = l >> 4;
    const int wm = w >> 1, wn = w & 1;
    const int slr = l >> 3, slc = l & 7;

    const unsigned short* srcA[4];
    const unsigned short* srcB[4];
#pragma unroll
    for (int i = 0; i < 4; ++i) {
        int s = w * 4 + i;
        int r = s * 8 + slr;
        int pr = m0 + r; if (pr > Ne - 1) pr = Ne - 1;
        srcA[i] = Abuf + (size_t)(off + pr) * F_DIM + (slc ^ (r & 7)) * 8;
        srcB[i] = wdT + ((size_t)e * H_DIM + bn0 + r) * F_DIM + (slc ^ (r & 7)) * 8;
    }

    int aoff[4][2], boff[4][2];
#pragma unroll
    for (int m = 0; m < 4; ++m) {
        int row = wm * 64 + m * 16 + llo;
        int brow = wn * 64 + m * 16 + llo;
#pragma unroll
        for (int kk = 0; kk < 2; ++kk) {
            aoff[m][kk] = row * 128 + (((kk * 4 + lhi) ^ (row & 7)) * 16);
            boff[m][kk] = brow * 128 + (((kk * 4 + lhi) ^ (brow & 7)) * 16);
        }
    }

    f32x4 acc[4][4] = {};

    for (int k0 = 0; k0 < F_DIM; k0 += 64) {
        __syncthreads();
#pragma unroll
        for (int i = 0; i < 4; ++i) {
            gload_lds16(srcA[i] + k0, (char*)sA + (w * 4 + i) * 1024);
            gload_lds16(srcB[i] + k0, sB + (w * 4 + i) * 1024);
        }
        asm volatile("s_waitcnt vmcnt(0)" ::: "memory");
        __syncthreads();

#pragma unroll
        for (int kk = 0; kk < 2; ++kk) {
            bf16x8 af[4], bfr[4];
#pragma unroll
            for (int m = 0; m < 4; ++m) {
                af[m]  = *(const bf16x8*)((const char*)sA + aoff[m][kk]);
                bfr[m] = *(const bf16x8*)(sB + boff[m][kk]);
            }
            __builtin_amdgcn_s_setprio(1);
#pragma unroll
            for (int m = 0; m < 4; ++m)
#pragma unroll
                for (int n = 0; n < 4; ++n)
                    acc[m][n] = __builtin_amdgcn_mfma_f32_16x16x32_bf16(af[m], bfr[n], acc[m][n], 0, 0, 0);
            __builtin_amdgcn_s_setprio(0);
        }
    }

    // epilogue: bf16 stores to per-pair rows (combine kernel does the weighted sum)
#pragma unroll
    for (int m = 0; m < 4; ++m) {
#pragma unroll
        for (int r = 0; r < 4; ++r) {
            int grow = m0 + wm * 64 + m * 16 + lhi * 4 + r;
            if (grow < Ne) {
                size_t p = (size_t)(off + grow);
#pragma unroll
                for (int n = 0; n < 4; ++n)
                    dbuf[p * H_DIM + bn0 + wn * 64 + n * 16 + llo] = f2bf(acc[m][n][r]);
            }
        }
    }
}

// ---------------- combine: out[t] = w0*d[p0] + w1*d[p1] (bf16 dbuf) ----------------
__global__ __launch_bounds__(256) void combine_kernel(
    const unsigned short* __restrict__ dbuf, const int* __restrict__ inv_pos,
    const float* __restrict__ top_w, float* __restrict__ out)
{
    int tok = blockIdx.x;
    int p0 = inv_pos[tok * 2], p1 = inv_pos[tok * 2 + 1];
    float w0 = top_w[tok * 2], w1 = top_w[tok * 2 + 1];
    int c = threadIdx.x * 4;
    ushort4 a = *(const ushort4*)&dbuf[(size_t)p0 * H_DIM + c];
    ushort4 b = *(const ushort4*)&dbuf[(size_t)p1 * H_DIM + c];
    union { uint32_t u; float f; } ca, cb;
    float4 o;
    ca.u = (uint32_t)a.x << 16; cb.u = (uint32_t)b.x << 16; o.x = w0 * ca.f + w1 * cb.f;
    ca.u = (uint32_t)a.y << 16; cb.u = (uint32_t)b.y << 16; o.y = w0 * ca.f + w1 * cb.f;
    ca.u = (uint32_t)a.z << 16; cb.u = (uint32_t)b.z << 16; o.z = w0 * ca.f + w1 * cb.f;
    ca.u = (uint32_t)a.w << 16; cb.u = (uint32_t)b.w << 16; o.w = w0 * ca.f + w1 * cb.f;
    *(float4*)&out[(size_t)tok * H_DIM + c] = o;
}

extern "C" void kernel_launch(void* const* d_in, const int* in_sizes, int n_in,
                              void* d_out, int out_size, void* d_ws, size_t ws_size,
                              hipStream_t stream)
{
    const float* x  = (const float*)d_in[0];
    const float* wr = (const float*)d_in[1];
    const float* wg = (const float*)d_in[2];
    const float* wu = (const float*)d_in[3];
    const float* wd = (const float*)d_in[4];
    float* out = (float*)d_out;

    char* ws = (char*)d_ws;
    const size_t WT = (size_t)NE * F_DIM * H_DIM * 2;            // 46,137,344 B
    unsigned short* wgT  = (unsigned short*)(ws);                // reused as wdT after gemm1
    unsigned short* wuT  = (unsigned short*)(ws + WT);           // reused as dbuf (bf16) after gemm1
    unsigned short* Abuf = (unsigned short*)(ws + 2 * WT);
    unsigned short* xbf  = (unsigned short*)(ws + 3 * WT);
    char* misc = ws + 3 * WT + (size_t)T_TOK * H_DIM * 2;
    int*   pair_tok = (int*)(misc);
    int*   top_i    = (int*)(misc + 32768);
    float* top_w    = (float*)(misc + 65536);
    int*   inv_pos  = (int*)(misc + 98304);
    int*   counts   = (int*)(misc + 131072);
    int*   offsets  = counts + 8;
    int*   wtab     = offsets + 9;
    unsigned short* wdT = wgT;
    unsigned short* dbuf = wuT;

    hipMemsetAsync(counts, 0, 8 * sizeof(int), stream);

    transpose_cvt_gu3<<<dim3(F_DIM / 64, H_DIM / 64, 16), 256, 0, stream>>>(wg, wu, wgT, wuT);
    router_kernel<<<T_TOK / 4, 256, 0, stream>>>(x, wr, xbf, top_i, top_w, counts);
    prefix_scatter_kernel<<<1, 256, 0, stream>>>(counts, top_i, offsets, wtab, pair_tok, inv_pos);
    gemm1_kernel<<<dim3(F_DIM / 64, NTILE_MAX), 256, 0, stream>>>(xbf, wgT, wuT, pair_tok, offsets, wtab, Abuf);
    transpose_cvt_v3<<<dim3(H_DIM / 64, F_DIM / 64, NE), 256, 0, stream>>>(wd, wdT, F_DIM, H_DIM);
    gemm2_kernel<<<dim3(H_DIM / 128, NTILE_MAX), 256, 0, stream>>>(Abuf, wdT, offsets, wtab, dbuf);
    combine_kernel<<<T_TOK, 256, 0, stream>>>(dbuf, inv_pos, top_w, out);
}

// Round 8
// 309.582 us; speedup vs baseline: 1.4320x; 1.2160x over previous
//
#include <hip/hip_runtime.h>
#include <hip/hip_bf16.h>
#include <stdint.h>

#define T_TOK 4096
#define H_DIM 1024
#define F_DIM 2816
#define NE 8
#define NTILE_MAX 72   // >= sum_e ceil(Ne/128) worst case (64 + 7 partials)

using bf16x8 = __attribute__((ext_vector_type(8))) short;   // 8 bf16 in 4 VGPRs
using f32x16 = __attribute__((ext_vector_type(16))) float;  // 32x32 MFMA accumulator

// RNE float -> bf16 bits (finite inputs only)
__device__ __forceinline__ unsigned short f2bf(float f) {
    union { float f; uint32_t u; } v; v.f = f;
    uint32_t r = v.u + 0x7FFFu + ((v.u >> 16) & 1u);
    return (unsigned short)(r >> 16);
}

// async global->LDS, 16B per lane. lds dest: wave-uniform base + lane*16.
__device__ __forceinline__ void gload_lds16(const void* gsrc, void* lds) {
    __builtin_amdgcn_global_load_lds(
        (const __attribute__((address_space(1))) uint32_t*)gsrc,
        (__attribute__((address_space(3))) uint32_t*)lds, 16, 0, 0);
}

// ---------------- router: one wave per token; also emits xbf (bf16 cast of x) ----------------
__global__ __launch_bounds__(256) void router_kernel(
    const float* __restrict__ x, const float* __restrict__ wr,
    unsigned short* __restrict__ xbf,
    int* __restrict__ top_i, float* __restrict__ top_w)
{
    const int w = threadIdx.x >> 6, l = threadIdx.x & 63;
    const int tok = blockIdx.x * 4 + w;
    const float* xrow = x + (size_t)tok * H_DIM;
    unsigned short* xbrow = xbf + (size_t)tok * H_DIM;
    float acc[NE] = {};
    for (int h = l; h < H_DIM; h += 64) {
        float xv = xrow[h];
        xbrow[h] = f2bf(xv);
#pragma unroll
        for (int e = 0; e < NE; e++) acc[e] += xv * wr[h * NE + e];
    }
#pragma unroll
    for (int e = 0; e < NE; e++) {
        for (int off = 32; off; off >>= 1) acc[e] += __shfl_xor(acc[e], off);
    }
    if (l == 0) {
        int i1 = 0; float b1 = acc[0];
#pragma unroll
        for (int e = 1; e < NE; e++) if (acc[e] > b1) { b1 = acc[e]; i1 = e; }
        int i2 = -1; float b2 = -1e30f;
#pragma unroll
        for (int e = 0; e < NE; e++) if (e != i1 && acc[e] > b2) { b2 = acc[e]; i2 = e; }
        float w1 = 1.0f / (1.0f + __expf(b2 - b1));   // exact renormalized top-2
        top_i[tok * 2] = i1; top_i[tok * 2 + 1] = i2;
        top_w[tok * 2] = w1; top_w[tok * 2 + 1] = 1.0f - w1;
    }
}

// ---------------- fused count + prefix + work-table + scatter (single block) ----------------
__global__ __launch_bounds__(256) void prefix_scatter_kernel(
    const int* __restrict__ top_i,
    int* __restrict__ offsets, int* __restrict__ wtab,
    int* __restrict__ pair_tok, int* __restrict__ inv_pos)
{
    __shared__ int scnt[NE];
    __shared__ int scur[NE];
    if (threadIdx.x < NE) scnt[threadIdx.x] = 0;
    __syncthreads();
    for (int tok = threadIdx.x; tok < T_TOK; tok += 256) {
        atomicAdd(&scnt[top_i[tok * 2]], 1);
        atomicAdd(&scnt[top_i[tok * 2 + 1]], 1);
    }
    __syncthreads();
    if (threadIdx.x == 0) {
        int s = 0;
        for (int e = 0; e < NE; e++) { offsets[e] = s; scur[e] = s; s += scnt[e]; }
        offsets[NE] = s;
        int idx = 0;
        for (int e = 0; e < NE; e++) {
            int nt = (scnt[e] + 127) >> 7;
            for (int mt = 0; mt < nt && idx < NTILE_MAX; ++mt) wtab[idx++] = (e << 16) | mt;
        }
        while (idx < NTILE_MAX) wtab[idx++] = -1;
    }
    __syncthreads();
    for (int tok = threadIdx.x; tok < T_TOK; tok += 256) {
#pragma unroll
        for (int k = 0; k < 2; k++) {
            int e = top_i[tok * 2 + k];
            int pos = atomicAdd(&scur[e], 1);
            pair_tok[pos] = tok;
            inv_pos[tok * 2 + k] = pos;
        }
    }
}

// ---------------- transpose+cvt v3: in[R][C] f32 -> out[C][R] bf16, 64x64 tile ----------------
__device__ __forceinline__ void transpose_tile_v3(
    const float* __restrict__ inp, unsigned short* __restrict__ oute,
    int R, int C, int r0, int c0, int t)
{
    __shared__ uint32_t tile[64][33];
#pragma unroll
    for (int p = 0; p < 4; ++p) {
        int r = p * 16 + (t >> 4);
        float4 v = *(const float4*)&inp[(size_t)(r0 + r) * C + c0 + (t & 15) * 4];
        tile[r][(t & 15) * 2]     = (uint32_t)f2bf(v.x) | ((uint32_t)f2bf(v.y) << 16);
        tile[r][(t & 15) * 2 + 1] = (uint32_t)f2bf(v.z) | ((uint32_t)f2bf(v.w) << 16);
    }
    __syncthreads();
#pragma unroll
    for (int p = 0; p < 2; ++p) {
        int oc = p * 32 + (t >> 3);
        int rb = (t & 7) * 8;
        int cp = oc >> 1, sh = (oc & 1) * 16;
        unsigned short u[8];
#pragma unroll
        for (int i = 0; i < 8; ++i) u[i] = (unsigned short)(tile[rb + i][cp] >> sh);
        uint4 o;
        o.x = (uint32_t)u[0] | ((uint32_t)u[1] << 16);
        o.y = (uint32_t)u[2] | ((uint32_t)u[3] << 16);
        o.z = (uint32_t)u[4] | ((uint32_t)u[5] << 16);
        o.w = (uint32_t)u[6] | ((uint32_t)u[7] << 16);
        *(uint4*)&oute[(size_t)(c0 + oc) * R + r0 + rb] = o;
    }
}

// generic: in[e][R][C] -> out[e][C][R]
__global__ __launch_bounds__(256) void transpose_cvt_v3(
    const float* __restrict__ in, unsigned short* __restrict__ outp, int R, int C)
{
    const int e = blockIdx.z;
    transpose_tile_v3(in + (size_t)e * R * C, outp + (size_t)e * R * C,
                      R, C, blockIdx.y * 64, blockIdx.x * 64, threadIdx.x);
}

// gate+up fused: z<8 -> wg[e=z], z>=8 -> wu[e=z-8]; R=H, C=F
__global__ __launch_bounds__(256) void transpose_cvt_gu3(
    const float* __restrict__ wg, const float* __restrict__ wu,
    unsigned short* __restrict__ wgT, unsigned short* __restrict__ wuT)
{
    const int z = blockIdx.z;
    const int e = z & 7;
    const float* inp = (z < 8 ? wg : wu) + (size_t)e * H_DIM * F_DIM;
    unsigned short* oute = (z < 8 ? wgT : wuT) + (size_t)e * H_DIM * F_DIM;
    transpose_tile_v3(inp, oute, H_DIM, F_DIM,
                      blockIdx.y * 64, blockIdx.x * 64, threadIdx.x);
}

// ---------------- GEMM1: m97-style, 128 rows x 64 f (gate+up), BK=64, 32KB LDS ----------------
// 32x32x16 MFMA: A lane row=l&31, k=(l>>5)*8+j; C/D col=lane&31, row=(reg&3)+8*(reg>>2)+4*(lane>>5).
// grid: (x = f-panel [44] FAST, y = m-tile [72])
__global__ __launch_bounds__(256, 4) void gemm1_kernel(
    const unsigned short* __restrict__ xbf,
    const unsigned short* __restrict__ wgT,
    const unsigned short* __restrict__ wuT,
    const int* __restrict__ pair_tok, const int* __restrict__ offsets,
    const int* __restrict__ wtab,
    unsigned short* __restrict__ Abuf)
{
    const int wv = wtab[blockIdx.y];
    if (wv < 0) return;
    const int e = wv >> 16;
    const int m0 = (wv & 0xFFFF) * 128;
    const int off = offsets[e], Ne = offsets[e + 1] - off;
    const int bn0 = blockIdx.x * 64;

    __shared__ unsigned short smem[16384];   // 32KB
    unsigned short* sA = smem;               // bytes [0, 16384)
    char* sG = (char*)smem + 16384;          // [16384, 24576)
    char* sU = (char*)smem + 24576;          // [24576, 32768)

    const int t = threadIdx.x, l = t & 63, w = t >> 6;
    const int l31 = l & 31, h5 = l >> 5;
    const int wm = w >> 1, wn = w & 1;
    const int slr = l >> 3, slc = l & 7;     // staging: row-in-seg, chunk

    const unsigned short* srcA[4];
#pragma unroll
    for (int i = 0; i < 4; ++i) {
        int s = w * 4 + i;
        int r = s * 8 + slr;
        int pr = m0 + r; if (pr > Ne - 1) pr = Ne - 1;
        srcA[i] = xbf + (size_t)pair_tok[off + pr] * H_DIM + (slc ^ (r & 7)) * 8;
    }
    const unsigned short* srcG[2];
    const unsigned short* srcU[2];
#pragma unroll
    for (int i = 0; i < 2; ++i) {
        int s = w * 2 + i;
        int fr = s * 8 + slr;
        srcG[i] = wgT + ((size_t)e * F_DIM + bn0 + fr) * H_DIM + (slc ^ (fr & 7)) * 8;
        srcU[i] = wuT + ((size_t)e * F_DIM + bn0 + fr) * H_DIM + (slc ^ (fr & 7)) * 8;
    }

    // fragment byte offsets: kk = K-16 step (0..3), chunk c = kk*2 + h5
    int aoff[2][4], goff[4];
#pragma unroll
    for (int mm = 0; mm < 2; ++mm) {
        int row = wm * 64 + mm * 32 + l31;
#pragma unroll
        for (int kk = 0; kk < 4; ++kk)
            aoff[mm][kk] = row * 128 + (((kk * 2 + h5) ^ (row & 7)) * 16);
    }
    {
        int g = wn * 32 + l31;
#pragma unroll
        for (int kk = 0; kk < 4; ++kk)
            goff[kk] = g * 128 + (((kk * 2 + h5) ^ (g & 7)) * 16);
    }

    f32x16 accG[2] = {}, accU[2] = {};

    for (int k0 = 0; k0 < H_DIM; k0 += 64) {
        __syncthreads();
#pragma unroll
        for (int i = 0; i < 4; ++i)
            gload_lds16(srcA[i] + k0, (char*)sA + (w * 4 + i) * 1024);
#pragma unroll
        for (int i = 0; i < 2; ++i) {
            gload_lds16(srcG[i] + k0, sG + (w * 2 + i) * 1024);
            gload_lds16(srcU[i] + k0, sU + (w * 2 + i) * 1024);
        }
        asm volatile("s_waitcnt vmcnt(0)" ::: "memory");
        __syncthreads();

#pragma unroll
        for (int kk = 0; kk < 4; ++kk) {
            bf16x8 a0 = *(const bf16x8*)((const char*)sA + aoff[0][kk]);
            bf16x8 a1 = *(const bf16x8*)((const char*)sA + aoff[1][kk]);
            bf16x8 gf = *(const bf16x8*)(sG + goff[kk]);
            bf16x8 uf = *(const bf16x8*)(sU + goff[kk]);
            __builtin_amdgcn_s_setprio(1);
            accG[0] = __builtin_amdgcn_mfma_f32_32x32x16_bf16(a0, gf, accG[0], 0, 0, 0);
            accG[1] = __builtin_amdgcn_mfma_f32_32x32x16_bf16(a1, gf, accG[1], 0, 0, 0);
            accU[0] = __builtin_amdgcn_mfma_f32_32x32x16_bf16(a0, uf, accU[0], 0, 0, 0);
            accU[1] = __builtin_amdgcn_mfma_f32_32x32x16_bf16(a1, uf, accU[1], 0, 0, 0);
            __builtin_amdgcn_s_setprio(0);
        }
    }

    // epilogue: silu(g)*u -> bf16. 32x32 C/D: col=l31, row=(r&3)+8*(r>>2)+4*h5
#pragma unroll
    for (int mm = 0; mm < 2; ++mm) {
#pragma unroll
        for (int r = 0; r < 16; ++r) {
            int grow = m0 + wm * 64 + mm * 32 + (r & 3) + 8 * (r >> 2) + 4 * h5;
            if (grow < Ne) {
                size_t p = (size_t)(off + grow);
                float g = accG[mm][r], u = accU[mm][r];
                float a = g / (1.0f + __expf(-g)) * u;
                Abuf[p * F_DIM + bn0 + wn * 32 + l31] = f2bf(a);
            }
        }
    }
}

// ---------------- GEMM2: m97-style, 128 x 128, BK=64, 32KB LDS, writes bf16 dbuf ----------------
// grid: (x = h-panel [8] FAST, y = m-tile [72])
__global__ __launch_bounds__(256, 4) void gemm2_kernel(
    const unsigned short* __restrict__ Abuf,
    const unsigned short* __restrict__ wdT,
    const int* __restrict__ offsets, const int* __restrict__ wtab,
    unsigned short* __restrict__ dbuf)
{
    const int wv = wtab[blockIdx.y];
    if (wv < 0) return;
    const int e = wv >> 16;
    const int m0 = (wv & 0xFFFF) * 128;
    const int off = offsets[e], Ne = offsets[e + 1] - off;
    const int bn0 = blockIdx.x * 128;

    __shared__ unsigned short smem[16384];   // 32KB: A 16KB | B 16KB
    unsigned short* sA = smem;
    char* sB = (char*)smem + 16384;

    const int t = threadIdx.x, l = t & 63, w = t >> 6;
    const int l31 = l & 31, h5 = l >> 5;
    const int wm = w >> 1, wn = w & 1;
    const int slr = l >> 3, slc = l & 7;

    const unsigned short* srcA[4];
    const unsigned short* srcB[4];
#pragma unroll
    for (int i = 0; i < 4; ++i) {
        int s = w * 4 + i;
        int r = s * 8 + slr;
        int pr = m0 + r; if (pr > Ne - 1) pr = Ne - 1;
        srcA[i] = Abuf + (size_t)(off + pr) * F_DIM + (slc ^ (r & 7)) * 8;
        srcB[i] = wdT + ((size_t)e * H_DIM + bn0 + r) * F_DIM + (slc ^ (r & 7)) * 8;
    }

    int aoff[2][4], boff[2][4];
#pragma unroll
    for (int mm = 0; mm < 2; ++mm) {
        int row = wm * 64 + mm * 32 + l31;
        int brow = wn * 64 + mm * 32 + l31;
#pragma unroll
        for (int kk = 0; kk < 4; ++kk) {
            aoff[mm][kk] = row * 128 + (((kk * 2 + h5) ^ (row & 7)) * 16);
            boff[mm][kk] = brow * 128 + (((kk * 2 + h5) ^ (brow & 7)) * 16);
        }
    }

    f32x16 acc[2][2] = {};

    for (int k0 = 0; k0 < F_DIM; k0 += 64) {
        __syncthreads();
#pragma unroll
        for (int i = 0; i < 4; ++i) {
            gload_lds16(srcA[i] + k0, (char*)sA + (w * 4 + i) * 1024);
            gload_lds16(srcB[i] + k0, sB + (w * 4 + i) * 1024);
        }
        asm volatile("s_waitcnt vmcnt(0)" ::: "memory");
        __syncthreads();

#pragma unroll
        for (int kk = 0; kk < 4; ++kk) {
            bf16x8 a0  = *(const bf16x8*)((const char*)sA + aoff[0][kk]);
            bf16x8 a1  = *(const bf16x8*)((const char*)sA + aoff[1][kk]);
            bf16x8 b0  = *(const bf16x8*)(sB + boff[0][kk]);
            bf16x8 b1  = *(const bf16x8*)(sB + boff[1][kk]);
            __builtin_amdgcn_s_setprio(1);
            acc[0][0] = __builtin_amdgcn_mfma_f32_32x32x16_bf16(a0, b0, acc[0][0], 0, 0, 0);
            acc[0][1] = __builtin_amdgcn_mfma_f32_32x32x16_bf16(a0, b1, acc[0][1], 0, 0, 0);
            acc[1][0] = __builtin_amdgcn_mfma_f32_32x32x16_bf16(a1, b0, acc[1][0], 0, 0, 0);
            acc[1][1] = __builtin_amdgcn_mfma_f32_32x32x16_bf16(a1, b1, acc[1][1], 0, 0, 0);
            __builtin_amdgcn_s_setprio(0);
        }
    }

    // epilogue: bf16 stores to per-pair rows (combine kernel does the weighted sum)
#pragma unroll
    for (int mm = 0; mm < 2; ++mm) {
#pragma unroll
        for (int r = 0; r < 16; ++r) {
            int grow = m0 + wm * 64 + mm * 32 + (r & 3) + 8 * (r >> 2) + 4 * h5;
            if (grow < Ne) {
                size_t p = (size_t)(off + grow);
#pragma unroll
                for (int nn = 0; nn < 2; ++nn)
                    dbuf[p * H_DIM + bn0 + wn * 64 + nn * 32 + l31] = f2bf(acc[mm][nn][r]);
            }
        }
    }
}

// ---------------- combine: out[t] = w0*d[p0] + w1*d[p1] (bf16 dbuf) ----------------
__global__ __launch_bounds__(256) void combine_kernel(
    const unsigned short* __restrict__ dbuf, const int* __restrict__ inv_pos,
    const float* __restrict__ top_w, float* __restrict__ out)
{
    int tok = blockIdx.x;
    int p0 = inv_pos[tok * 2], p1 = inv_pos[tok * 2 + 1];
    float w0 = top_w[tok * 2], w1 = top_w[tok * 2 + 1];
    int c = threadIdx.x * 4;
    ushort4 a = *(const ushort4*)&dbuf[(size_t)p0 * H_DIM + c];
    ushort4 b = *(const ushort4*)&dbuf[(size_t)p1 * H_DIM + c];
    union { uint32_t u; float f; } ca, cb;
    float4 o;
    ca.u = (uint32_t)a.x << 16; cb.u = (uint32_t)b.x << 16; o.x = w0 * ca.f + w1 * cb.f;
    ca.u = (uint32_t)a.y << 16; cb.u = (uint32_t)b.y << 16; o.y = w0 * ca.f + w1 * cb.f;
    ca.u = (uint32_t)a.z << 16; cb.u = (uint32_t)b.z << 16; o.z = w0 * ca.f + w1 * cb.f;
    ca.u = (uint32_t)a.w << 16; cb.u = (uint32_t)b.w << 16; o.w = w0 * ca.f + w1 * cb.f;
    *(float4*)&out[(size_t)tok * H_DIM + c] = o;
}

extern "C" void kernel_launch(void* const* d_in, const int* in_sizes, int n_in,
                              void* d_out, int out_size, void* d_ws, size_t ws_size,
                              hipStream_t stream)
{
    const float* x  = (const float*)d_in[0];
    const float* wr = (const float*)d_in[1];
    const float* wg = (const float*)d_in[2];
    const float* wu = (const float*)d_in[3];
    const float* wd = (const float*)d_in[4];
    float* out = (float*)d_out;

    char* ws = (char*)d_ws;
    const size_t WT = (size_t)NE * F_DIM * H_DIM * 2;            // 46,137,344 B
    unsigned short* wgT  = (unsigned short*)(ws);                // reused as wdT after gemm1
    unsigned short* wuT  = (unsigned short*)(ws + WT);           // reused as dbuf (bf16) after gemm1
    unsigned short* Abuf = (unsigned short*)(ws + 2 * WT);
    unsigned short* xbf  = (unsigned short*)(ws + 3 * WT);
    char* misc = ws + 3 * WT + (size_t)T_TOK * H_DIM * 2;
    int*   pair_tok = (int*)(misc);
    int*   top_i    = (int*)(misc + 32768);
    float* top_w    = (float*)(misc + 65536);
    int*   inv_pos  = (int*)(misc + 98304);
    int*   offsets  = (int*)(misc + 131072);
    int*   wtab     = offsets + 9;
    unsigned short* wdT = wgT;
    unsigned short* dbuf = wuT;

    transpose_cvt_gu3<<<dim3(F_DIM / 64, H_DIM / 64, 16), 256, 0, stream>>>(wg, wu, wgT, wuT);
    router_kernel<<<T_TOK / 4, 256, 0, stream>>>(x, wr, xbf, top_i, top_w);
    prefix_scatter_kernel<<<1, 256, 0, stream>>>(top_i, offsets, wtab, pair_tok, inv_pos);
    gemm1_kernel<<<dim3(F_DIM / 64, NTILE_MAX), 256, 0, stream>>>(xbf, wgT, wuT, pair_tok, offsets, wtab, Abuf);
    transpose_cvt_v3<<<dim3(H_DIM / 64, F_DIM / 64, NE), 256, 0, stream>>>(wd, wdT, F_DIM, H_DIM);
    gemm2_kernel<<<dim3(H_DIM / 128, NTILE_MAX), 256, 0, stream>>>(Abuf, wdT, offsets, wtab, dbuf);
    combine_kernel<<<T_TOK, 256, 0, stream>>>(dbuf, inv_pos, top_w, out);
}

// Round 9
// 291.919 us; speedup vs baseline: 1.5187x; 1.0605x over previous
//
#include <hip/hip_runtime.h>
#include <hip/hip_bf16.h>
#include <stdint.h>

#define T_TOK 4096
#define H_DIM 1024
#define F_DIM 2816
#define NE 8
#define NPAIR (T_TOK * 2)
#define NTILE_MAX 72   // >= sum_e ceil(Ne/128) worst case (64 + 7 partials)

using bf16x8 = __attribute__((ext_vector_type(8))) short;   // 8 bf16 in 4 VGPRs
using f32x4  = __attribute__((ext_vector_type(4))) float;   // 16x16 MFMA accumulator
using f32x16 = __attribute__((ext_vector_type(16))) float;  // 32x32 MFMA accumulator

// RNE float -> bf16 bits (finite inputs only)
__device__ __forceinline__ unsigned short f2bf(float f) {
    union { float f; uint32_t u; } v; v.f = f;
    uint32_t r = v.u + 0x7FFFu + ((v.u >> 16) & 1u);
    return (unsigned short)(r >> 16);
}

// async global->LDS, 16B per lane. lds dest: wave-uniform base + lane*16.
__device__ __forceinline__ void gload_lds16(const void* gsrc, void* lds) {
    __builtin_amdgcn_global_load_lds(
        (const __attribute__((address_space(1))) uint32_t*)gsrc,
        (__attribute__((address_space(3))) uint32_t*)lds, 16, 0, 0);
}

// ---------------- router: one wave per token; also emits xbf (bf16 cast of x) ----------------
__global__ __launch_bounds__(256) void router_kernel(
    const float* __restrict__ x, const float* __restrict__ wr,
    unsigned short* __restrict__ xbf,
    int* __restrict__ top_i, float* __restrict__ top_w)
{
    const int w = threadIdx.x >> 6, l = threadIdx.x & 63;
    const int tok = blockIdx.x * 4 + w;
    const float* xrow = x + (size_t)tok * H_DIM;
    unsigned short* xbrow = xbf + (size_t)tok * H_DIM;
    float acc[NE] = {};
    for (int h = l; h < H_DIM; h += 64) {
        float xv = xrow[h];
        xbrow[h] = f2bf(xv);
#pragma unroll
        for (int e = 0; e < NE; e++) acc[e] += xv * wr[h * NE + e];
    }
#pragma unroll
    for (int e = 0; e < NE; e++) {
        for (int off = 32; off; off >>= 1) acc[e] += __shfl_xor(acc[e], off);
    }
    if (l == 0) {
        int i1 = 0; float b1 = acc[0];
#pragma unroll
        for (int e = 1; e < NE; e++) if (acc[e] > b1) { b1 = acc[e]; i1 = e; }
        int i2 = -1; float b2 = -1e30f;
#pragma unroll
        for (int e = 0; e < NE; e++) if (e != i1 && acc[e] > b2) { b2 = acc[e]; i2 = e; }
        float w1 = 1.0f / (1.0f + __expf(b2 - b1));   // exact renormalized top-2
        top_i[tok * 2] = i1; top_i[tok * 2 + 1] = i2;
        top_w[tok * 2] = w1; top_w[tok * 2 + 1] = 1.0f - w1;
    }
}

// ---------------- fused count + prefix + work-table + scatter (single block) ----------------
__global__ __launch_bounds__(256) void prefix_scatter_kernel(
    const int* __restrict__ top_i,
    int* __restrict__ offsets, int* __restrict__ wtab,
    int* __restrict__ pair_tok, int* __restrict__ inv_pos)
{
    __shared__ int scnt[NE];
    __shared__ int scur[NE];
    if (threadIdx.x < NE) scnt[threadIdx.x] = 0;
    __syncthreads();
    for (int tok = threadIdx.x; tok < T_TOK; tok += 256) {
        atomicAdd(&scnt[top_i[tok * 2]], 1);
        atomicAdd(&scnt[top_i[tok * 2 + 1]], 1);
    }
    __syncthreads();
    if (threadIdx.x == 0) {
        int s = 0;
        for (int e = 0; e < NE; e++) { offsets[e] = s; scur[e] = s; s += scnt[e]; }
        offsets[NE] = s;
        int idx = 0;
        for (int e = 0; e < NE; e++) {
            int nt = (scnt[e] + 127) >> 7;
            for (int mt = 0; mt < nt && idx < NTILE_MAX; ++mt) wtab[idx++] = (e << 16) | mt;
        }
        while (idx < NTILE_MAX) wtab[idx++] = -1;
    }
    __syncthreads();
    for (int tok = threadIdx.x; tok < T_TOK; tok += 256) {
#pragma unroll
        for (int k = 0; k < 2; k++) {
            int e = top_i[tok * 2 + k];
            int pos = atomicAdd(&scur[e], 1);
            pair_tok[pos] = tok;
            inv_pos[tok * 2 + k] = pos;
        }
    }
}

// ---------------- transpose+cvt v3: in[R][C] f32 -> out[C][R] bf16, 64x64 tile ----------------
__device__ __forceinline__ void transpose_tile_v3(
    const float* __restrict__ inp, unsigned short* __restrict__ oute,
    int R, int C, int r0, int c0, int t)
{
    __shared__ uint32_t tile[64][33];
#pragma unroll
    for (int p = 0; p < 4; ++p) {
        int r = p * 16 + (t >> 4);
        float4 v = *(const float4*)&inp[(size_t)(r0 + r) * C + c0 + (t & 15) * 4];
        tile[r][(t & 15) * 2]     = (uint32_t)f2bf(v.x) | ((uint32_t)f2bf(v.y) << 16);
        tile[r][(t & 15) * 2 + 1] = (uint32_t)f2bf(v.z) | ((uint32_t)f2bf(v.w) << 16);
    }
    __syncthreads();
#pragma unroll
    for (int p = 0; p < 2; ++p) {
        int oc = p * 32 + (t >> 3);
        int rb = (t & 7) * 8;
        int cp = oc >> 1, sh = (oc & 1) * 16;
        unsigned short u[8];
#pragma unroll
        for (int i = 0; i < 8; ++i) u[i] = (unsigned short)(tile[rb + i][cp] >> sh);
        uint4 o;
        o.x = (uint32_t)u[0] | ((uint32_t)u[1] << 16);
        o.y = (uint32_t)u[2] | ((uint32_t)u[3] << 16);
        o.z = (uint32_t)u[4] | ((uint32_t)u[5] << 16);
        o.w = (uint32_t)u[6] | ((uint32_t)u[7] << 16);
        *(uint4*)&oute[(size_t)(c0 + oc) * R + r0 + rb] = o;
    }
}

// generic: in[e][R][C] -> out[e][C][R]
__global__ __launch_bounds__(256) void transpose_cvt_v3(
    const float* __restrict__ in, unsigned short* __restrict__ outp, int R, int C)
{
    const int e = blockIdx.z;
    transpose_tile_v3(in + (size_t)e * R * C, outp + (size_t)e * R * C,
                      R, C, blockIdx.y * 64, blockIdx.x * 64, threadIdx.x);
}

// gate+up fused: z<8 -> wg[e=z], z>=8 -> wu[e=z-8]; R=H, C=F
__global__ __launch_bounds__(256) void transpose_cvt_gu3(
    const float* __restrict__ wg, const float* __restrict__ wu,
    unsigned short* __restrict__ wgT, unsigned short* __restrict__ wuT)
{
    const int z = blockIdx.z;
    const int e = z & 7;
    const float* inp = (z < 8 ? wg : wu) + (size_t)e * H_DIM * F_DIM;
    unsigned short* oute = (z < 8 ? wgT : wuT) + (size_t)e * H_DIM * F_DIM;
    transpose_tile_v3(inp, oute, H_DIM, F_DIM,
                      blockIdx.y * 64, blockIdx.x * 64, threadIdx.x);
}

// ---------------- GEMM1: m97-style, 128 rows x 64 f (gate+up), BK=64, 32KB LDS ----------------
// 16x16x32 MFMA (measured conflict-free fragment pattern). grid: (x=f-panel FAST, y=m-tile)
__global__ __launch_bounds__(256, 4) void gemm1_kernel(
    const unsigned short* __restrict__ xbf,
    const unsigned short* __restrict__ wgT,
    const unsigned short* __restrict__ wuT,
    const int* __restrict__ pair_tok, const int* __restrict__ offsets,
    const int* __restrict__ wtab,
    unsigned short* __restrict__ Abuf)
{
    const int wv = wtab[blockIdx.y];
    if (wv < 0) return;
    const int e = wv >> 16;
    const int m0 = (wv & 0xFFFF) * 128;
    const int off = offsets[e], Ne = offsets[e + 1] - off;
    const int bn0 = blockIdx.x * 64;

    __shared__ unsigned short smem[16384];   // 32KB
    unsigned short* sA = smem;               // bytes [0, 16384)
    char* sG = (char*)smem + 16384;          // [16384, 24576)
    char* sU = (char*)smem + 24576;          // [24576, 32768)

    const int t = threadIdx.x, l = t & 63, w = t >> 6;
    const int llo = l & 15, lhi = l >> 4;
    const int wm = w >> 1, wn = w & 1;
    const int slr = l >> 3, slc = l & 7;     // staging: row-in-seg, chunk

    const unsigned short* srcA[4];
#pragma unroll
    for (int i = 0; i < 4; ++i) {
        int s = w * 4 + i;
        int r = s * 8 + slr;
        int pr = m0 + r; if (pr > Ne - 1) pr = Ne - 1;
        srcA[i] = xbf + (size_t)pair_tok[off + pr] * H_DIM + (slc ^ (r & 7)) * 8;
    }
    const unsigned short* srcG[2];
    const unsigned short* srcU[2];
#pragma unroll
    for (int i = 0; i < 2; ++i) {
        int s = w * 2 + i;
        int fr = s * 8 + slr;
        srcG[i] = wgT + ((size_t)e * F_DIM + bn0 + fr) * H_DIM + (slc ^ (fr & 7)) * 8;
        srcU[i] = wuT + ((size_t)e * F_DIM + bn0 + fr) * H_DIM + (slc ^ (fr & 7)) * 8;
    }

    int aoff[4][2], goff[2][2];
#pragma unroll
    for (int m = 0; m < 4; ++m) {
        int row = wm * 64 + m * 16 + llo;
#pragma unroll
        for (int kk = 0; kk < 2; ++kk)
            aoff[m][kk] = row * 128 + (((kk * 4 + lhi) ^ (row & 7)) * 16);
    }
#pragma unroll
    for (int n = 0; n < 2; ++n) {
        int g = wn * 32 + n * 16 + llo;
#pragma unroll
        for (int kk = 0; kk < 2; ++kk)
            goff[n][kk] = g * 128 + (((kk * 4 + lhi) ^ (g & 7)) * 16);
    }

    f32x4 accG[4][2] = {}, accU[4][2] = {};

    for (int k0 = 0; k0 < H_DIM; k0 += 64) {
        __syncthreads();
#pragma unroll
        for (int i = 0; i < 4; ++i)
            gload_lds16(srcA[i] + k0, (char*)sA + (w * 4 + i) * 1024);
#pragma unroll
        for (int i = 0; i < 2; ++i) {
            gload_lds16(srcG[i] + k0, sG + (w * 2 + i) * 1024);
            gload_lds16(srcU[i] + k0, sU + (w * 2 + i) * 1024);
        }
        asm volatile("s_waitcnt vmcnt(0)" ::: "memory");
        __syncthreads();

#pragma unroll
        for (int kk = 0; kk < 2; ++kk) {
            bf16x8 af[4], gf[2], uf[2];
#pragma unroll
            for (int m = 0; m < 4; ++m) af[m] = *(const bf16x8*)((const char*)sA + aoff[m][kk]);
#pragma unroll
            for (int n = 0; n < 2; ++n) {
                gf[n] = *(const bf16x8*)(sG + goff[n][kk]);
                uf[n] = *(const bf16x8*)(sU + goff[n][kk]);
            }
            __builtin_amdgcn_s_setprio(1);
#pragma unroll
            for (int m = 0; m < 4; ++m)
#pragma unroll
                for (int n = 0; n < 2; ++n) {
                    accG[m][n] = __builtin_amdgcn_mfma_f32_16x16x32_bf16(af[m], gf[n], accG[m][n], 0, 0, 0);
                    accU[m][n] = __builtin_amdgcn_mfma_f32_16x16x32_bf16(af[m], uf[n], accU[m][n], 0, 0, 0);
                }
            __builtin_amdgcn_s_setprio(0);
        }
    }

    // epilogue: silu(g)*u -> bf16. C/D: col=lane&15, row=(lane>>4)*4+reg
#pragma unroll
    for (int m = 0; m < 4; ++m) {
#pragma unroll
        for (int r = 0; r < 4; ++r) {
            int grow = m0 + wm * 64 + m * 16 + lhi * 4 + r;
            if (grow < Ne) {
                size_t p = (size_t)(off + grow);
#pragma unroll
                for (int n = 0; n < 2; ++n) {
                    float g = accG[m][n][r], u = accU[m][n][r];
                    float a = g / (1.0f + __expf(-g)) * u;
                    Abuf[p * F_DIM + bn0 + wn * 32 + n * 16 + llo] = f2bf(a);
                }
            }
        }
    }
}

// ---------------- GEMM2: 32x32x16 MFMA, 128 x 128, BK=64, K-split x2, writes bf16 dbuf ----------------
// grid: (x = h-panel [8] FAST, y = m-tile [72], z = K-half [2])
__global__ __launch_bounds__(256, 4) void gemm2_kernel(
    const unsigned short* __restrict__ Abuf,
    const unsigned short* __restrict__ wdT,
    const int* __restrict__ offsets, const int* __restrict__ wtab,
    unsigned short* __restrict__ dbuf)
{
    const int wv = wtab[blockIdx.y];
    if (wv < 0) return;
    const int e = wv >> 16;
    const int m0 = (wv & 0xFFFF) * 128;
    const int off = offsets[e], Ne = offsets[e + 1] - off;
    const int bn0 = blockIdx.x * 128;
    const int kbase = blockIdx.z * (F_DIM / 2);   // K-split half
    unsigned short* dout = dbuf + (size_t)blockIdx.z * NPAIR * H_DIM;

    __shared__ unsigned short smem[16384];   // 32KB: A 16KB | B 16KB
    unsigned short* sA = smem;
    char* sB = (char*)smem + 16384;

    const int t = threadIdx.x, l = t & 63, w = t >> 6;
    const int l31 = l & 31, h5 = l >> 5;
    const int wm = w >> 1, wn = w & 1;
    const int slr = l >> 3, slc = l & 7;

    const unsigned short* srcA[4];
    const unsigned short* srcB[4];
#pragma unroll
    for (int i = 0; i < 4; ++i) {
        int s = w * 4 + i;
        int r = s * 8 + slr;
        int pr = m0 + r; if (pr > Ne - 1) pr = Ne - 1;
        srcA[i] = Abuf + (size_t)(off + pr) * F_DIM + kbase + (slc ^ (r & 7)) * 8;
        srcB[i] = wdT + ((size_t)e * H_DIM + bn0 + r) * F_DIM + kbase + (slc ^ (r & 7)) * 8;
    }

    int aoff[2][4], boff[2][4];
#pragma unroll
    for (int mm = 0; mm < 2; ++mm) {
        int row = wm * 64 + mm * 32 + l31;
        int brow = wn * 64 + mm * 32 + l31;
#pragma unroll
        for (int kk = 0; kk < 4; ++kk) {
            aoff[mm][kk] = row * 128 + (((kk * 2 + h5) ^ (row & 7)) * 16);
            boff[mm][kk] = brow * 128 + (((kk * 2 + h5) ^ (brow & 7)) * 16);
        }
    }

    f32x16 acc[2][2] = {};

    for (int k0 = 0; k0 < F_DIM / 2; k0 += 64) {
        __syncthreads();
#pragma unroll
        for (int i = 0; i < 4; ++i) {
            gload_lds16(srcA[i] + k0, (char*)sA + (w * 4 + i) * 1024);
            gload_lds16(srcB[i] + k0, sB + (w * 4 + i) * 1024);
        }
        asm volatile("s_waitcnt vmcnt(0)" ::: "memory");
        __syncthreads();

#pragma unroll
        for (int kk = 0; kk < 4; ++kk) {
            bf16x8 a0  = *(const bf16x8*)((const char*)sA + aoff[0][kk]);
            bf16x8 a1  = *(const bf16x8*)((const char*)sA + aoff[1][kk]);
            bf16x8 b0  = *(const bf16x8*)(sB + boff[0][kk]);
            bf16x8 b1  = *(const bf16x8*)(sB + boff[1][kk]);
            __builtin_amdgcn_s_setprio(1);
            acc[0][0] = __builtin_amdgcn_mfma_f32_32x32x16_bf16(a0, b0, acc[0][0], 0, 0, 0);
            acc[0][1] = __builtin_amdgcn_mfma_f32_32x32x16_bf16(a0, b1, acc[0][1], 0, 0, 0);
            acc[1][0] = __builtin_amdgcn_mfma_f32_32x32x16_bf16(a1, b0, acc[1][0], 0, 0, 0);
            acc[1][1] = __builtin_amdgcn_mfma_f32_32x32x16_bf16(a1, b1, acc[1][1], 0, 0, 0);
            __builtin_amdgcn_s_setprio(0);
        }
    }

    // epilogue: bf16 partials. 32x32 C/D: col=l31, row=(r&3)+8*(r>>2)+4*h5
#pragma unroll
    for (int mm = 0; mm < 2; ++mm) {
#pragma unroll
        for (int r = 0; r < 16; ++r) {
            int grow = m0 + wm * 64 + mm * 32 + (r & 3) + 8 * (r >> 2) + 4 * h5;
            if (grow < Ne) {
                size_t p = (size_t)(off + grow);
#pragma unroll
                for (int nn = 0; nn < 2; ++nn)
                    dout[p * H_DIM + bn0 + wn * 64 + nn * 32 + l31] = f2bf(acc[mm][nn][r]);
            }
        }
    }
}

// ---------------- combine: out[t] = w0*(d0[p0]+d1[p0]) + w1*(d0[p1]+d1[p1]) ----------------
__global__ __launch_bounds__(256) void combine_kernel(
    const unsigned short* __restrict__ dbuf, const int* __restrict__ inv_pos,
    const float* __restrict__ top_w, float* __restrict__ out)
{
    int tok = blockIdx.x;
    int p0 = inv_pos[tok * 2], p1 = inv_pos[tok * 2 + 1];
    float w0 = top_w[tok * 2], w1 = top_w[tok * 2 + 1];
    const unsigned short* d1 = dbuf + (size_t)NPAIR * H_DIM;
    int c = threadIdx.x * 4;
    ushort4 a0 = *(const ushort4*)&dbuf[(size_t)p0 * H_DIM + c];
    ushort4 a1 = *(const ushort4*)&d1[(size_t)p0 * H_DIM + c];
    ushort4 b0 = *(const ushort4*)&dbuf[(size_t)p1 * H_DIM + c];
    ushort4 b1 = *(const ushort4*)&d1[(size_t)p1 * H_DIM + c];
    union { uint32_t u; float f; } va, vb, vc, vd;
    float4 o;
    va.u = (uint32_t)a0.x << 16; vb.u = (uint32_t)a1.x << 16; vc.u = (uint32_t)b0.x << 16; vd.u = (uint32_t)b1.x << 16;
    o.x = w0 * (va.f + vb.f) + w1 * (vc.f + vd.f);
    va.u = (uint32_t)a0.y << 16; vb.u = (uint32_t)a1.y << 16; vc.u = (uint32_t)b0.y << 16; vd.u = (uint32_t)b1.y << 16;
    o.y = w0 * (va.f + vb.f) + w1 * (vc.f + vd.f);
    va.u = (uint32_t)a0.z << 16; vb.u = (uint32_t)a1.z << 16; vc.u = (uint32_t)b0.z << 16; vd.u = (uint32_t)b1.z << 16;
    o.z = w0 * (va.f + vb.f) + w1 * (vc.f + vd.f);
    va.u = (uint32_t)a0.w << 16; vb.u = (uint32_t)a1.w << 16; vc.u = (uint32_t)b0.w << 16; vd.u = (uint32_t)b1.w << 16;
    o.w = w0 * (va.f + vb.f) + w1 * (vc.f + vd.f);
    *(float4*)&out[(size_t)tok * H_DIM + c] = o;
}

extern "C" void kernel_launch(void* const* d_in, const int* in_sizes, int n_in,
                              void* d_out, int out_size, void* d_ws, size_t ws_size,
                              hipStream_t stream)
{
    const float* x  = (const float*)d_in[0];
    const float* wr = (const float*)d_in[1];
    const float* wg = (const float*)d_in[2];
    const float* wu = (const float*)d_in[3];
    const float* wd = (const float*)d_in[4];
    float* out = (float*)d_out;

    char* ws = (char*)d_ws;
    const size_t WT = (size_t)NE * F_DIM * H_DIM * 2;            // 46,137,344 B
    unsigned short* wgT  = (unsigned short*)(ws);                // reused as wdT after gemm1
    unsigned short* wuT  = (unsigned short*)(ws + WT);           // reused as dbuf (bf16 x2 halves) after gemm1
    unsigned short* Abuf = (unsigned short*)(ws + 2 * WT);
    unsigned short* xbf  = (unsigned short*)(ws + 3 * WT);
    char* misc = ws + 3 * WT + (size_t)T_TOK * H_DIM * 2;
    int*   pair_tok = (int*)(misc);
    int*   top_i    = (int*)(misc + 32768);
    float* top_w    = (float*)(misc + 65536);
    int*   inv_pos  = (int*)(misc + 98304);
    int*   offsets  = (int*)(misc + 131072);
    int*   wtab     = offsets + 9;
    unsigned short* wdT = wgT;
    unsigned short* dbuf = wuT;   // 2 x NPAIR x H_DIM bf16 = 33.5 MB < WT

    transpose_cvt_gu3<<<dim3(F_DIM / 64, H_DIM / 64, 16), 256, 0, stream>>>(wg, wu, wgT, wuT);
    router_kernel<<<T_TOK / 4, 256, 0, stream>>>(x, wr, xbf, top_i, top_w);
    prefix_scatter_kernel<<<1, 256, 0, stream>>>(top_i, offsets, wtab, pair_tok, inv_pos);
    gemm1_kernel<<<dim3(F_DIM / 64, NTILE_MAX), 256, 0, stream>>>(xbf, wgT, wuT, pair_tok, offsets, wtab, Abuf);
    transpose_cvt_v3<<<dim3(H_DIM / 64, F_DIM / 64, NE), 256, 0, stream>>>(wd, wdT, F_DIM, H_DIM);
    gemm2_kernel<<<dim3(H_DIM / 128, NTILE_MAX, 2), 256, 0, stream>>>(Abuf, wdT, offsets, wtab, dbuf);
    combine_kernel<<<T_TOK, 256, 0, stream>>>(dbuf, inv_pos, top_w, out);
}